// Round 10
// baseline (859.051 us; speedup 1.0000x reference)
//
#include <hip/hip_runtime.h>
#include <hip/hip_bf16.h>

#define NUM_TX   100000
#define NUM_USER 30000
#define NUM_DEV  10000
#define NN       140000   // total nodes
#define MP       140032   // NN padded to multiple of 128
#define NSLOT    1094     // MP/128 row-block slots
#define INC      128
#define HID      256
#define NEDGE    1000000
#define BN_EPS   1e-5f
#define SCAN_NB  548      // ceil((NN+1)/256)
#define NPART    137      // ceil(NN/1024) dst partitions for 2-pass scatter
#define P1_NB    64       // pass-1 blocks
#define P1_CHUNK 15625    // NEDGE / P1_NB (exact)
#define CH_CAP   35072    // chunk-row cap (multiple of 128): AGG chunk <= 71.8 MB for L3 residency

typedef __attribute__((ext_vector_type(8))) short bf16x8;
typedef __attribute__((ext_vector_type(4))) float f32x4;

__device__ __forceinline__ float b2f(unsigned short s) {
    union { unsigned int u; float f; } c; c.u = ((unsigned int)s) << 16; return c.f;
}
__device__ __forceinline__ unsigned short f2b(float f) {
    union { __hip_bfloat16 h; unsigned short s; } c; c.h = __float2bfloat16(f); return c.s;
}

// ---------------- diagnostic fallback: encode ws_size into the output ----------------
__global__ void mark_ws(float* __restrict__ out, int n, float val) {
    int i = blockIdx.x * 256 + threadIdx.x;
    if (i < n) out[i] = val;
}

// ---------------- edge preprocessing ----------------
__global__ void count_edges(const int* __restrict__ ei, int* __restrict__ cnt) {
    int e = blockIdx.x * 256 + threadIdx.x;
    if (e >= NEDGE) return;
    atomicAdd(&cnt[ei[NEDGE + e]], 1);
}

__global__ void scan_bsum(const int* __restrict__ cnt, int* __restrict__ bsum) {
    int t = threadIdx.x;
    int i = blockIdx.x * 256 + t;
    int v = (i < NN) ? cnt[i] : 0;
    __shared__ int ls[4];
#pragma unroll
    for (int d = 32; d; d >>= 1) v += __shfl_down(v, d);
    if ((t & 63) == 0) ls[t >> 6] = v;
    __syncthreads();
    if (t == 0) bsum[blockIdx.x] = ls[0] + ls[1] + ls[2] + ls[3];
}

__global__ void scan_bscan(int* __restrict__ bsum) {
    __shared__ int ss[1024];
    int t = threadIdx.x;
    int v = (t < SCAN_NB) ? bsum[t] : 0;
    ss[t] = v;
    __syncthreads();
    for (int d = 1; d < 1024; d <<= 1) {
        int u = (t >= d) ? ss[t - d] : 0;
        __syncthreads();
        ss[t] += u;
        __syncthreads();
    }
    if (t < SCAN_NB) bsum[t] = ss[t] - v;   // exclusive
}

__global__ void scan_final(const int* __restrict__ cnt, const int* __restrict__ bsum,
                           int* __restrict__ off) {
    __shared__ int ss[256];
    int t = threadIdx.x;
    int i = blockIdx.x * 256 + t;
    int v = (i < NN) ? cnt[i] : 0;
    ss[t] = v;
    __syncthreads();
    for (int d = 1; d < 256; d <<= 1) {
        int u = (t >= d) ? ss[t - d] : 0;
        __syncthreads();
        ss[t] += u;
        __syncthreads();
    }
    if (i <= NN) off[i] = bsum[blockIdx.x] + ss[t] - v;
}

// ---- 2-pass partition scatter ----
// Pass 1: per-block LDS histogram over 137 dst-partitions -> one padded global
// atomic per (block,partition) -> ranked contiguous writes of packed u64 records
// into the partition's ptmp region (region base = eoff[p<<10], free from CSR).
__global__ __launch_bounds__(256) void scatter_part1(
    const int* __restrict__ ei, const int* __restrict__ et,
    const int* __restrict__ eoff, int* __restrict__ pctr,
    unsigned long long* __restrict__ ptmp) {
    __shared__ int hist[NPART];
    __shared__ int base[NPART];
    __shared__ int runc[NPART];
    int b = blockIdx.x, t = threadIdx.x;
    int e0 = b * P1_CHUNK, e1 = e0 + P1_CHUNK;
    for (int i = t; i < NPART; i += 256) { hist[i] = 0; runc[i] = 0; }
    __syncthreads();
    for (int e = e0 + t; e < e1; e += 256)
        atomicAdd(&hist[ei[NEDGE + e] >> 10], 1);
    __syncthreads();
    if (t < NPART)
        base[t] = eoff[t << 10] + atomicAdd(&pctr[t * 16], hist[t]);  // padded counters: 1 line each
    __syncthreads();
    for (int e = e0 + t; e < e1; e += 256) {
        int dst = ei[NEDGE + e];
        int p = dst >> 10;
        int r = atomicAdd(&runc[p], 1);
        unsigned long long w = (unsigned long long)(unsigned)ei[e]
                             | ((unsigned long long)(unsigned)et[e] << 18)
                             | ((unsigned long long)(unsigned)dst << 20);
        ptmp[(size_t)base[p] + r] = w;
    }
}

// Pass 2: one block per partition; coalesced record read, final scatter inside a
// ~29KB L2-resident window, per-dst counters in LDS (no global atomics).
__global__ __launch_bounds__(256) void scatter_part2(
    const int* __restrict__ eoff, const unsigned long long* __restrict__ ptmp,
    int* __restrict__ sedge) {
    __shared__ int lctr[1024];
    int p = blockIdx.x, t = threadIdx.x;
    int n0 = p << 10;
    int n1 = n0 + 1024; if (n1 > NN) n1 = NN;
    for (int i = t; i < 1024; i += 256) lctr[i] = 0;
    __syncthreads();
    int lo = eoff[n0], hi = eoff[n1];
    for (int j = lo + t; j < hi; j += 256) {
        unsigned long long w = ptmp[j];
        int src = (int)(w & 0x3FFFF);
        int rel = (int)((w >> 18) & 3);
        int dst = (int)(w >> 20);
        int r = atomicAdd(&lctr[dst - n0], 1);
        sedge[eoff[dst] + r] = src | (rel << 28);
    }
}

// ---------------- input / weight staging ----------------
__global__ void build_x0(const float* __restrict__ xt, const float* __restrict__ ue,
                         const float* __restrict__ de, unsigned short* __restrict__ X) {
    int tid = blockIdx.x * 256 + threadIdx.x;   // NN*32 threads (exact)
    int i = tid >> 5;
    int c4 = (tid & 31) << 2;
    const float* s;
    if (i < NUM_TX) s = xt + (size_t)i * INC;
    else if (i < NUM_TX + NUM_USER) s = ue + (size_t)(i - NUM_TX) * INC;
    else s = de + (size_t)(i - NUM_TX - NUM_USER) * INC;
    float4 v = *(const float4*)(s + c4);
    ushort4 o;
    o.x = f2b(v.x); o.y = f2b(v.y); o.z = f2b(v.z); o.w = f2b(v.w);
    *(ushort4*)(X + (size_t)i * INC + c4) = o;
}

// Wt[n*K + k] = bf16( k<rootK ? root[k][n] : rel[(k-rootK)][n] )  (n-major for GEMM B^T)
__global__ void build_wt(const float* __restrict__ rootw, const float* __restrict__ relw,
                         unsigned short* __restrict__ Wt, int K, int rootK) {
    int tid = blockIdx.x * 256 + threadIdx.x;   // 256*K threads (grid = K blocks, exact)
    int n = tid / K, k = tid - n * K;
    float v = (k < rootK) ? rootw[(size_t)k * HID + n] : relw[(size_t)(k - rootK) * HID + n];
    Wt[tid] = f2b(v);
}

// ---------------- segmented mean aggregation (all 4 relations, one edge walk) ----------------
template<int C>
__global__ __launch_bounds__(256) void aggregate(
    const unsigned short* __restrict__ X, unsigned short* __restrict__ AGG,
    const int* __restrict__ eoff, const int* __restrict__ sedge, int m0) {
    constexpr int V = C / 64;
    int w = threadIdx.x >> 6, lane = threadIdx.x & 63;
    int i = m0 + blockIdx.x * 4 + w;
    if (i >= NN) return;
    float a0[V] = {}, a1[V] = {}, a2[V] = {}, a3[V] = {};
    int c0 = 0, c1 = 0, c2 = 0, c3 = 0;
    int b = eoff[i], e = eoff[i + 1];
    for (int p = b; p < e; ++p) {
        int pe = sedge[p];                 // wave-uniform
        int src = pe & 0x0FFFFFFF;
        int r = pe >> 28;
        const unsigned short* row = X + (size_t)src * C + lane * V;
        float v[V];
        if constexpr (V == 2) {
            unsigned int u = *(const unsigned int*)row;
            v[0] = b2f((unsigned short)(u & 0xFFFF));
            v[1] = b2f((unsigned short)(u >> 16));
        } else {
            ushort4 u = *(const ushort4*)row;
            v[0] = b2f(u.x); v[1] = b2f(u.y); v[2] = b2f(u.z); v[3] = b2f(u.w);
        }
        switch (r) {                       // wave-uniform branch
            case 0:  { for (int j = 0; j < V; ++j) a0[j] += v[j]; c0++; } break;
            case 1:  { for (int j = 0; j < V; ++j) a1[j] += v[j]; c1++; } break;
            case 2:  { for (int j = 0; j < V; ++j) a2[j] += v[j]; c2++; } break;
            default: { for (int j = 0; j < V; ++j) a3[j] += v[j]; c3++; } break;
        }
    }
    float s0 = 1.0f / (float)(c0 > 1 ? c0 : 1);
    float s1 = 1.0f / (float)(c1 > 1 ? c1 : 1);
    float s2 = 1.0f / (float)(c2 > 1 ? c2 : 1);
    float s3 = 1.0f / (float)(c3 > 1 ? c3 : 1);
    unsigned short* orow = AGG + (size_t)(i - m0) * (4 * C) + lane * V;
#pragma unroll
    for (int j = 0; j < V; ++j) {
        orow[0 * C + j] = f2b(a0[j] * s0);
        orow[1 * C + j] = f2b(a1[j] * s1);
        orow[2 * C + j] = f2b(a2[j] * s2);
        orow[3 * C + j] = f2b(a3[j] * s3);
    }
}

// ---------------- bf16 MFMA GEMM (split-source A, dbuf + counted vmcnt, XOR-swizzled LDS)
// + fused BN column-stat partials + XCD-pairing swizzle (keep: r9 win) ----
template<int C>
__global__ __launch_bounds__(256) void gemm_split(
    const unsigned short* __restrict__ Xg, const unsigned short* __restrict__ AGGg,
    const unsigned short* __restrict__ Wt, unsigned short* __restrict__ Cg,
    const float* __restrict__ bias, float* __restrict__ partialC, int mblocks, int m0) {
    constexpr int K = 5 * C;
    constexpr int NKT = K / 64;
    constexpr int XKT = C / 64;
    __shared__ unsigned short As[2][128 * 64];
    __shared__ unsigned short Bs[2][128 * 64];
    __shared__ float sred[2][2][4][16][2];   // [wr][wc][j][l15][{s,s2}]
    int bid = blockIdx.x;
    int bm = (bid & 7) + ((bid >> 4) << 3);
    int bn = (bid >> 3) & 1;
    if (bm >= mblocks) return;               // pad blocks from grid round-up
    int t = threadIdx.x;
    int lane = t & 63, w = t >> 6;
    int wr = w >> 1, wc = w & 1;
    int l15 = lane & 15, l7 = lane & 7, hi = lane >> 4;
    f32x4 acc[4][4] = {};
    const int rowA0 = bm * 128, rowB0 = bn * 128;

    auto STAGE = [&](int buf, int kt) {
#pragma unroll
        for (int it = 0; it < 4; ++it) {
            int R = it * 32 + (t >> 3);
            int sl = (t & 7) ^ (R & 7);           // pre-swizzled global slot
            const unsigned short* ga;
            if (kt < XKT)
                ga = Xg + (size_t)(m0 + rowA0 + R) * C + kt * 64 + sl * 8;
            else
                ga = AGGg + (size_t)(rowA0 + R) * (4 * C) + (kt - XKT) * 64 + sl * 8;
            __builtin_amdgcn_global_load_lds(
                (const __attribute__((address_space(1))) void*)ga,
                (__attribute__((address_space(3))) void*)(&As[buf][it * 2048 + t * 8]), 16, 0, 0);
            const unsigned short* gb = Wt + (size_t)(rowB0 + R) * K + kt * 64 + sl * 8;
            __builtin_amdgcn_global_load_lds(
                (const __attribute__((address_space(1))) void*)gb,
                (__attribute__((address_space(3))) void*)(&Bs[buf][it * 2048 + t * 8]), 16, 0, 0);
        }
    };

    STAGE(0, 0);
    int cur = 0;
    for (int kt = 0; kt < NKT; ++kt) {
        if (kt + 1 < NKT) {
            STAGE(cur ^ 1, kt + 1);
            asm volatile("s_waitcnt vmcnt(8)" ::: "memory");
        } else {
            asm volatile("s_waitcnt vmcnt(0)" ::: "memory");
        }
        __builtin_amdgcn_s_barrier();
        __builtin_amdgcn_sched_barrier(0);
        const unsigned short* as = As[cur];
        const unsigned short* bs = Bs[cur];
#pragma unroll
        for (int kk = 0; kk < 64; kk += 32) {
            bf16x8 af[4], bfr[4];
            int sl2 = (((kk >> 3) + hi) ^ l7) << 3;
#pragma unroll
            for (int f = 0; f < 4; ++f) {
                int m = wr * 64 + f * 16 + l15;
                af[f] = *(const bf16x8*)(as + m * 64 + sl2);
                int n = wc * 64 + f * 16 + l15;
                bfr[f] = *(const bf16x8*)(bs + n * 64 + sl2);
            }
#pragma unroll
            for (int i = 0; i < 4; ++i)
#pragma unroll
                for (int j = 0; j < 4; ++j)
                    acc[i][j] = __builtin_amdgcn_mfma_f32_16x16x32_bf16(af[i], bfr[j], acc[i][j], 0, 0, 0);
        }
        __builtin_amdgcn_s_barrier();
        __builtin_amdgcn_sched_barrier(0);
        cur ^= 1;
    }

    // ---- epilogue: C-write + fused BN partial sums ----
#pragma unroll
    for (int j = 0; j < 4; ++j) {
        int n = rowB0 + wc * 64 + j * 16 + l15;
        float bs = bias[n];
        float s = 0.f, q2 = 0.f;
#pragma unroll
        for (int i = 0; i < 4; ++i)
#pragma unroll
            for (int q = 0; q < 4; ++q) {
                int ml = rowA0 + wr * 64 + i * 16 + hi * 4 + q;   // local chunk row
                float v = acc[i][j][q] + bs;
                Cg[(size_t)ml * HID + n] = f2b(v);
                if (m0 + ml < NN) { s += v; q2 += v * v; }        // exclude padding rows
            }
        s  += __shfl_down(s, 32);  s  += __shfl_down(s, 16);
        q2 += __shfl_down(q2, 32); q2 += __shfl_down(q2, 16);
        if (lane < 16) { sred[wr][wc][j][l15][0] = s; sred[wr][wc][j][l15][1] = q2; }
    }
    __syncthreads();
    if (t < 128) {   // one thread per block column
        int wcc = t >> 6, j = (t >> 4) & 3, li = t & 15;
        float s  = sred[0][wcc][j][li][0] + sred[1][wcc][j][li][0];
        float q2 = sred[0][wcc][j][li][1] + sred[1][wcc][j][li][1];
        int slot = (m0 >> 7) + bm;          // global 128-row slot, unique per (layer, slot)
        int cg = rowB0 + t;                 // global column 0..255
        partialC[(size_t)slot * 512 + cg] = s;
        partialC[(size_t)slot * 512 + 256 + cg] = q2;
    }
}

// ---------------- BN reduce (deterministic, hierarchical) ----------------
__global__ void bn_red1(const float* __restrict__ pc, float* __restrict__ t2) {
    int b = blockIdx.x;      // 64
    int ch = threadIdx.x;    // 256
    float s0 = 0.f, s1 = 0.f;
    for (int s = b; s < NSLOT; s += 64) {
        s0 += pc[(size_t)s * 512 + ch];
        s1 += pc[(size_t)s * 512 + 256 + ch];
    }
    t2[b * 512 + ch] = s0;
    t2[b * 512 + 256 + ch] = s1;
}

// MUST be launched with exactly HID(=256) threads; guard enforces the contract.
__global__ void bn_fin2(const float* __restrict__ t2, float* __restrict__ mi) {
    int ch = threadIdx.x;
    if (ch >= HID) return;
    float s = 0.f, q2 = 0.f;
    for (int b = 0; b < 64; ++b) {
        s += t2[b * 512 + ch];
        q2 += t2[b * 512 + 256 + ch];
    }
    float mean = s / (float)NN;
    float var = q2 / (float)NN - mean * mean;
    if (var < 0.f) var = 0.f;
    mi[ch] = mean;
    mi[HID + ch] = rsqrtf(var + BN_EPS);
}

// relu(bn(C)) -> bf16 into X2 (stride 256)
__global__ void bn_relu(const unsigned short* __restrict__ Cin, const float* __restrict__ mi,
                        const float* __restrict__ gamma, const float* __restrict__ beta,
                        unsigned short* __restrict__ Xout) {
    int tid = blockIdx.x * 256 + threadIdx.x;  // NN*64 threads (exact)
    int i = tid >> 6;
    int ch = (tid & 63) << 2;
    ushort4 v = *(const ushort4*)(Cin + (size_t)i * HID + ch);
    float vv[4] = { b2f(v.x), b2f(v.y), b2f(v.z), b2f(v.w) };
    ushort4 o;
    unsigned short* op = (unsigned short*)&o;
#pragma unroll
    for (int q = 0; q < 4; ++q) {
        int c = ch + q;
        float y = gamma[c] * (vv[q] - mi[c]) * mi[HID + c] + beta[c];
        op[q] = f2b(fmaxf(y, 0.f));
    }
    *(ushort4*)(Xout + (size_t)i * HID + ch) = o;
}

// fused bn2 + relu + classifier for tx rows: one wave per row
__global__ __launch_bounds__(256) void classify(
    const unsigned short* __restrict__ Cin, const float* __restrict__ mi,
    const float* __restrict__ gamma, const float* __restrict__ beta,
    const float* __restrict__ cw, const float* __restrict__ cb,
    float* __restrict__ out) {
    int w = threadIdx.x >> 6, lane = threadIdx.x & 63;
    int i = blockIdx.x * 4 + w;
    if (i >= NUM_TX) return;
    int ch = lane << 2;
    ushort4 v = *(const ushort4*)(Cin + (size_t)i * HID + ch);
    float vv[4] = { b2f(v.x), b2f(v.y), b2f(v.z), b2f(v.w) };
    float a0 = 0.f, a1 = 0.f;
#pragma unroll
    for (int q = 0; q < 4; ++q) {
        int c = ch + q;
        float y = gamma[c] * (vv[q] - mi[c]) * mi[HID + c] + beta[c];
        y = fmaxf(y, 0.f);
        a0 += y * cw[c * 2 + 0];
        a1 += y * cw[c * 2 + 1];
    }
#pragma unroll
    for (int d = 32; d; d >>= 1) { a0 += __shfl_down(a0, d); a1 += __shfl_down(a1, d); }
    if (lane == 0) {
        out[(size_t)i * 2 + 0] = a0 + cb[0];
        out[(size_t)i * 2 + 1] = a1 + cb[1];
    }
}

// ---------------- launch ----------------
extern "C" void kernel_launch(void* const* d_in, const int* in_sizes, int n_in,
                              void* d_out, int out_size, void* d_ws, size_t ws_size,
                              hipStream_t stream) {
    const float* x_tx   = (const float*)d_in[0];
    const float* ue     = (const float*)d_in[1];
    const float* de     = (const float*)d_in[2];
    const float* relw1  = (const float*)d_in[3];
    const float* rootw1 = (const float*)d_in[4];
    const float* bias1  = (const float*)d_in[5];
    const float* relw2  = (const float*)d_in[6];
    const float* rootw2 = (const float*)d_in[7];
    const float* bias2  = (const float*)d_in[8];
    const float* g1     = (const float*)d_in[9];
    const float* be1    = (const float*)d_in[10];
    const float* g2     = (const float*)d_in[11];
    const float* be2    = (const float*)d_in[12];
    const float* cw     = (const float*)d_in[13];
    const float* cb     = (const float*)d_in[14];
    const int*   ei     = (const int*)d_in[15];
    const int*   et     = (const int*)d_in[16];
    float* out = (float*)d_out;
    (void)in_sizes; (void)n_in;

    // ---- fixed workspace layout (~162 MB) ----
    char* p = (char*)d_ws;
    auto take = [&](size_t b) { char* r = p; p += (b + 255) & ~(size_t)255; return r; };
    unsigned short* X  = (unsigned short*)take((size_t)MP * HID * 2);  // X1 stride 128 / X2 stride 256
    unsigned short* Cb = (unsigned short*)take((size_t)MP * HID * 2);  // pre-BN activations, bf16
    unsigned short* Wt1 = (unsigned short*)take((size_t)HID * 640 * 2);
    unsigned short* Wt2 = (unsigned short*)take((size_t)HID * 1280 * 2);
    int* ecnt  = (int*)take((size_t)NN * 4);
    int* eoff  = (int*)take((size_t)(NN + 1) * 4);
    int* sedge = (int*)take((size_t)NEDGE * 4);
    unsigned long long* ptmp = (unsigned long long*)take((size_t)NEDGE * 8);
    int* pctr  = (int*)take((size_t)NPART * 16 * 4);   // padded: 1 line per counter
    int* bsum  = (int*)take((size_t)SCAN_NB * 4);
    float* partialC = (float*)take((size_t)NSLOT * 512 * 4);
    float* t2red    = (float*)take((size_t)64 * 512 * 4);
    float* mi1 = (float*)take(512 * 4);
    float* mi2 = (float*)take(512 * 4);
    size_t fixed = (size_t)(p - (char*)d_ws);

    // ---- adaptive AGG-chunk: CH rows of [4*256] bf16 (layer2 worst case) ----
    long long rem = (long long)ws_size - (long long)fixed;
    long long chv = rem / (4 * HID * 2);
    int CH = (chv >= 128) ? (int)(chv & ~127LL) : 0;
    if (CH > CH_CAP) CH = CH_CAP;
    if (CH < 128) {
        mark_ws<<<(out_size + 255) / 256, 256, 0, stream>>>(out, out_size, (float)(ws_size >> 20));
        return;
    }
    unsigned short* Achunk = (unsigned short*)take((size_t)CH * 4 * HID * 2);

    hipMemsetAsync(ecnt, 0, (size_t)NN * 4, stream);
    hipMemsetAsync(pctr, 0, (size_t)NPART * 16 * 4, stream);

    count_edges<<<(NEDGE + 255) / 256, 256, 0, stream>>>(ei, ecnt);
    scan_bsum<<<SCAN_NB, 256, 0, stream>>>(ecnt, bsum);
    scan_bscan<<<1, 1024, 0, stream>>>(bsum);
    scan_final<<<SCAN_NB, 256, 0, stream>>>(ecnt, bsum, eoff);
    scatter_part1<<<P1_NB, 256, 0, stream>>>(ei, et, eoff, pctr, ptmp);
    scatter_part2<<<NPART, 256, 0, stream>>>(eoff, ptmp, sedge);

    build_x0<<<NN * 32 / 256, 256, 0, stream>>>(x_tx, ue, de, X);
    build_wt<<<640, 256, 0, stream>>>(rootw1, relw1, Wt1, 640, 128);
    build_wt<<<1280, 256, 0, stream>>>(rootw2, relw2, Wt2, 1280, 256);

    // ---- layer 1 (C_in = 128, K = 640) ----
    for (int m0 = 0; m0 < MP; m0 += CH) {
        int rows = (MP - m0 < CH) ? (MP - m0) : CH;
        int mb = rows / 128;
        int grid = ((mb * 2 + 15) / 16) * 16;   // round up for the XCD-pair swizzle
        aggregate<128><<<rows / 4, 256, 0, stream>>>(X, Achunk, eoff, sedge, m0);
        gemm_split<128><<<grid, 256, 0, stream>>>(X, Achunk, Wt1, Cb + (size_t)m0 * HID, bias1, partialC, mb, m0);
    }
    bn_red1<<<64, 256, 0, stream>>>(partialC, t2red);
    bn_fin2<<<1, 256, 0, stream>>>(t2red, mi1);
    bn_relu<<<NN * 64 / 256, 256, 0, stream>>>(Cb, mi1, g1, be1, X);

    // ---- layer 2 (C_in = 256, K = 1280) ----
    for (int m0 = 0; m0 < MP; m0 += CH) {
        int rows = (MP - m0 < CH) ? (MP - m0) : CH;
        int mb = rows / 128;
        int grid = ((mb * 2 + 15) / 16) * 16;
        aggregate<256><<<rows / 4, 256, 0, stream>>>(X, Achunk, eoff, sedge, m0);
        gemm_split<256><<<grid, 256, 0, stream>>>(X, Achunk, Wt2, Cb + (size_t)m0 * HID, bias2, partialC, mb, m0);
    }
    bn_red1<<<64, 256, 0, stream>>>(partialC, t2red);
    bn_fin2<<<1, 256, 0, stream>>>(t2red, mi2);
    classify<<<NUM_TX / 4, 256, 0, stream>>>(Cb, mi2, g2, be2, cw, cb, out);
}

// Round 11
// 804.914 us; speedup vs baseline: 1.0673x; 1.0673x over previous
//
#include <hip/hip_runtime.h>
#include <hip/hip_bf16.h>

#define NUM_TX   100000
#define NUM_USER 30000
#define NUM_DEV  10000
#define NN       140000   // total nodes
#define MP       140032   // NN padded to multiple of 128
#define NSLOT    1094     // MP/128 row-block slots
#define INC      128
#define HID      256
#define NEDGE    1000000
#define BN_EPS   1e-5f
#define SCAN_NB  548      // ceil((NN+1)/256)
#define NPART    137      // ceil(NN/1024) dst partitions for 2-pass scatter
#define P1_NB    500      // pass-1 blocks (r10: 64 was occupancy-starved at 2.4%)
#define P1_CHUNK 2000     // NEDGE / P1_NB (exact)
#define CH_CAP   35072    // chunk-row cap (multiple of 128): AGG chunk <= 71.8 MB for L3 residency

typedef __attribute__((ext_vector_type(8))) short bf16x8;
typedef __attribute__((ext_vector_type(4))) float f32x4;

__device__ __forceinline__ float b2f(unsigned short s) {
    union { unsigned int u; float f; } c; c.u = ((unsigned int)s) << 16; return c.f;
}
__device__ __forceinline__ unsigned short f2b(float f) {
    union { __hip_bfloat16 h; unsigned short s; } c; c.h = __float2bfloat16(f); return c.s;
}

// ---------------- diagnostic fallback: encode ws_size into the output ----------------
__global__ void mark_ws(float* __restrict__ out, int n, float val) {
    int i = blockIdx.x * 256 + threadIdx.x;
    if (i < n) out[i] = val;
}

// ---------------- edge preprocessing ----------------
__global__ void count_edges(const int* __restrict__ ei, int* __restrict__ cnt) {
    int e = blockIdx.x * 256 + threadIdx.x;
    if (e >= NEDGE) return;
    atomicAdd(&cnt[ei[NEDGE + e]], 1);
}

__global__ void scan_bsum(const int* __restrict__ cnt, int* __restrict__ bsum) {
    int t = threadIdx.x;
    int i = blockIdx.x * 256 + t;
    int v = (i < NN) ? cnt[i] : 0;
    __shared__ int ls[4];
#pragma unroll
    for (int d = 32; d; d >>= 1) v += __shfl_down(v, d);
    if ((t & 63) == 0) ls[t >> 6] = v;
    __syncthreads();
    if (t == 0) bsum[blockIdx.x] = ls[0] + ls[1] + ls[2] + ls[3];
}

__global__ void scan_bscan(int* __restrict__ bsum) {
    __shared__ int ss[1024];
    int t = threadIdx.x;
    int v = (t < SCAN_NB) ? bsum[t] : 0;
    ss[t] = v;
    __syncthreads();
    for (int d = 1; d < 1024; d <<= 1) {
        int u = (t >= d) ? ss[t - d] : 0;
        __syncthreads();
        ss[t] += u;
        __syncthreads();
    }
    if (t < SCAN_NB) bsum[t] = ss[t] - v;   // exclusive
}

__global__ void scan_final(const int* __restrict__ cnt, const int* __restrict__ bsum,
                           int* __restrict__ off) {
    __shared__ int ss[256];
    int t = threadIdx.x;
    int i = blockIdx.x * 256 + t;
    int v = (i < NN) ? cnt[i] : 0;
    ss[t] = v;
    __syncthreads();
    for (int d = 1; d < 256; d <<= 1) {
        int u = (t >= d) ? ss[t - d] : 0;
        __syncthreads();
        ss[t] += u;
        __syncthreads();
    }
    if (i <= NN) off[i] = bsum[blockIdx.x] + ss[t] - v;
}

// ---- 2-pass partition scatter (r10: WRITE_SIZE 73->8.3 MB confirmed; r11: fix occupancy) ----
__global__ __launch_bounds__(256) void scatter_part1(
    const int* __restrict__ ei, const int* __restrict__ et,
    const int* __restrict__ eoff, int* __restrict__ pctr,
    unsigned long long* __restrict__ ptmp) {
    __shared__ int hist[NPART];
    __shared__ int base[NPART];
    __shared__ int runc[NPART];
    int b = blockIdx.x, t = threadIdx.x;
    int e0 = b * P1_CHUNK, e1 = e0 + P1_CHUNK;
    for (int i = t; i < NPART; i += 256) { hist[i] = 0; runc[i] = 0; }
    __syncthreads();
    for (int e = e0 + t; e < e1; e += 256)
        atomicAdd(&hist[ei[NEDGE + e] >> 10], 1);
    __syncthreads();
    if (t < NPART)
        base[t] = eoff[t << 10] + atomicAdd(&pctr[t * 16], hist[t]);  // padded counters: 1 line each
    __syncthreads();
    for (int e = e0 + t; e < e1; e += 256) {
        int dst = ei[NEDGE + e];
        int p = dst >> 10;
        int r = atomicAdd(&runc[p], 1);
        unsigned long long w = (unsigned long long)(unsigned)ei[e]
                             | ((unsigned long long)(unsigned)et[e] << 18)
                             | ((unsigned long long)(unsigned)dst << 20);
        ptmp[(size_t)base[p] + r] = w;
    }
}

// Pass 2: one block per partition; coalesced record read, final scatter inside a
// ~29KB L2-resident window, per-dst counters in LDS (no global atomics).
__global__ __launch_bounds__(1024) void scatter_part2(
    const int* __restrict__ eoff, const unsigned long long* __restrict__ ptmp,
    int* __restrict__ sedge) {
    __shared__ int lctr[1024];
    int p = blockIdx.x, t = threadIdx.x;
    int n0 = p << 10;
    int n1 = n0 + 1024; if (n1 > NN) n1 = NN;
    lctr[t] = 0;
    __syncthreads();
    int lo = eoff[n0], hi = eoff[n1];
    for (int j = lo + t; j < hi; j += 1024) {
        unsigned long long w = ptmp[j];
        int src = (int)(w & 0x3FFFF);
        int rel = (int)((w >> 18) & 3);
        int dst = (int)(w >> 20);
        int r = atomicAdd(&lctr[dst - n0], 1);
        sedge[eoff[dst] + r] = src | (rel << 28);
    }
}

// ---------------- input / weight staging ----------------
__global__ void build_x0(const float* __restrict__ xt, const float* __restrict__ ue,
                         const float* __restrict__ de, unsigned short* __restrict__ X) {
    int tid = blockIdx.x * 256 + threadIdx.x;   // NN*32 threads (exact)
    int i = tid >> 5;
    int c4 = (tid & 31) << 2;
    const float* s;
    if (i < NUM_TX) s = xt + (size_t)i * INC;
    else if (i < NUM_TX + NUM_USER) s = ue + (size_t)(i - NUM_TX) * INC;
    else s = de + (size_t)(i - NUM_TX - NUM_USER) * INC;
    float4 v = *(const float4*)(s + c4);
    ushort4 o;
    o.x = f2b(v.x); o.y = f2b(v.y); o.z = f2b(v.z); o.w = f2b(v.w);
    *(ushort4*)(X + (size_t)i * INC + c4) = o;
}

// Wt[n*K + k] = bf16( k<rootK ? root[k][n] : rel[(k-rootK)][n] )  (n-major for GEMM B^T)
__global__ void build_wt(const float* __restrict__ rootw, const float* __restrict__ relw,
                         unsigned short* __restrict__ Wt, int K, int rootK) {
    int tid = blockIdx.x * 256 + threadIdx.x;   // 256*K threads (grid = K blocks, exact)
    int n = tid / K, k = tid - n * K;
    float v = (k < rootK) ? rootw[(size_t)k * HID + n] : relw[(size_t)(k - rootK) * HID + n];
    Wt[tid] = f2b(v);
}

// ---------------- segmented mean aggregation (all 4 relations, one edge walk) ----------------
template<int C>
__global__ __launch_bounds__(256) void aggregate(
    const unsigned short* __restrict__ X, unsigned short* __restrict__ AGG,
    const int* __restrict__ eoff, const int* __restrict__ sedge, int m0) {
    constexpr int V = C / 64;
    int w = threadIdx.x >> 6, lane = threadIdx.x & 63;
    int i = m0 + blockIdx.x * 4 + w;
    if (i >= NN) return;
    float a0[V] = {}, a1[V] = {}, a2[V] = {}, a3[V] = {};
    int c0 = 0, c1 = 0, c2 = 0, c3 = 0;
    int b = eoff[i], e = eoff[i + 1];
    for (int p = b; p < e; ++p) {
        int pe = sedge[p];                 // wave-uniform
        int src = pe & 0x0FFFFFFF;
        int r = pe >> 28;
        const unsigned short* row = X + (size_t)src * C + lane * V;
        float v[V];
        if constexpr (V == 2) {
            unsigned int u = *(const unsigned int*)row;
            v[0] = b2f((unsigned short)(u & 0xFFFF));
            v[1] = b2f((unsigned short)(u >> 16));
        } else {
            ushort4 u = *(const ushort4*)row;
            v[0] = b2f(u.x); v[1] = b2f(u.y); v[2] = b2f(u.z); v[3] = b2f(u.w);
        }
        switch (r) {                       // wave-uniform branch
            case 0:  { for (int j = 0; j < V; ++j) a0[j] += v[j]; c0++; } break;
            case 1:  { for (int j = 0; j < V; ++j) a1[j] += v[j]; c1++; } break;
            case 2:  { for (int j = 0; j < V; ++j) a2[j] += v[j]; c2++; } break;
            default: { for (int j = 0; j < V; ++j) a3[j] += v[j]; c3++; } break;
        }
    }
    float s0 = 1.0f / (float)(c0 > 1 ? c0 : 1);
    float s1 = 1.0f / (float)(c1 > 1 ? c1 : 1);
    float s2 = 1.0f / (float)(c2 > 1 ? c2 : 1);
    float s3 = 1.0f / (float)(c3 > 1 ? c3 : 1);
    unsigned short* orow = AGG + (size_t)(i - m0) * (4 * C) + lane * V;
#pragma unroll
    for (int j = 0; j < V; ++j) {
        orow[0 * C + j] = f2b(a0[j] * s0);
        orow[1 * C + j] = f2b(a1[j] * s1);
        orow[2 * C + j] = f2b(a2[j] * s2);
        orow[3 * C + j] = f2b(a3[j] * s3);
    }
}

// ---------------- bf16 MFMA GEMM (split-source A, dbuf + counted vmcnt, XOR-swizzled LDS)
// + fused BN column-stat partials + XCD-pairing swizzle (keep: r9 win) ----
template<int C>
__global__ __launch_bounds__(256) void gemm_split(
    const unsigned short* __restrict__ Xg, const unsigned short* __restrict__ AGGg,
    const unsigned short* __restrict__ Wt, unsigned short* __restrict__ Cg,
    const float* __restrict__ bias, float* __restrict__ partialC, int mblocks, int m0) {
    constexpr int K = 5 * C;
    constexpr int NKT = K / 64;
    constexpr int XKT = C / 64;
    __shared__ unsigned short As[2][128 * 64];
    __shared__ unsigned short Bs[2][128 * 64];
    __shared__ float sred[2][2][4][16][2];   // [wr][wc][j][l15][{s,s2}]
    int bid = blockIdx.x;
    int bm = (bid & 7) + ((bid >> 4) << 3);
    int bn = (bid >> 3) & 1;
    if (bm >= mblocks) return;               // pad blocks from grid round-up
    int t = threadIdx.x;
    int lane = t & 63, w = t >> 6;
    int wr = w >> 1, wc = w & 1;
    int l15 = lane & 15, l7 = lane & 7, hi = lane >> 4;
    f32x4 acc[4][4] = {};
    const int rowA0 = bm * 128, rowB0 = bn * 128;

    auto STAGE = [&](int buf, int kt) {
#pragma unroll
        for (int it = 0; it < 4; ++it) {
            int R = it * 32 + (t >> 3);
            int sl = (t & 7) ^ (R & 7);           // pre-swizzled global slot
            const unsigned short* ga;
            if (kt < XKT)
                ga = Xg + (size_t)(m0 + rowA0 + R) * C + kt * 64 + sl * 8;
            else
                ga = AGGg + (size_t)(rowA0 + R) * (4 * C) + (kt - XKT) * 64 + sl * 8;
            __builtin_amdgcn_global_load_lds(
                (const __attribute__((address_space(1))) void*)ga,
                (__attribute__((address_space(3))) void*)(&As[buf][it * 2048 + t * 8]), 16, 0, 0);
            const unsigned short* gb = Wt + (size_t)(rowB0 + R) * K + kt * 64 + sl * 8;
            __builtin_amdgcn_global_load_lds(
                (const __attribute__((address_space(1))) void*)gb,
                (__attribute__((address_space(3))) void*)(&Bs[buf][it * 2048 + t * 8]), 16, 0, 0);
        }
    };

    STAGE(0, 0);
    int cur = 0;
    for (int kt = 0; kt < NKT; ++kt) {
        if (kt + 1 < NKT) {
            STAGE(cur ^ 1, kt + 1);
            asm volatile("s_waitcnt vmcnt(8)" ::: "memory");
        } else {
            asm volatile("s_waitcnt vmcnt(0)" ::: "memory");
        }
        __builtin_amdgcn_s_barrier();
        __builtin_amdgcn_sched_barrier(0);
        const unsigned short* as = As[cur];
        const unsigned short* bs = Bs[cur];
#pragma unroll
        for (int kk = 0; kk < 64; kk += 32) {
            bf16x8 af[4], bfr[4];
            int sl2 = (((kk >> 3) + hi) ^ l7) << 3;
#pragma unroll
            for (int f = 0; f < 4; ++f) {
                int m = wr * 64 + f * 16 + l15;
                af[f] = *(const bf16x8*)(as + m * 64 + sl2);
                int n = wc * 64 + f * 16 + l15;
                bfr[f] = *(const bf16x8*)(bs + n * 64 + sl2);
            }
#pragma unroll
            for (int i = 0; i < 4; ++i)
#pragma unroll
                for (int j = 0; j < 4; ++j)
                    acc[i][j] = __builtin_amdgcn_mfma_f32_16x16x32_bf16(af[i], bfr[j], acc[i][j], 0, 0, 0);
        }
        __builtin_amdgcn_s_barrier();
        __builtin_amdgcn_sched_barrier(0);
        cur ^= 1;
    }

    // ---- epilogue: C-write + fused BN partial sums ----
#pragma unroll
    for (int j = 0; j < 4; ++j) {
        int n = rowB0 + wc * 64 + j * 16 + l15;
        float bs = bias[n];
        float s = 0.f, q2 = 0.f;
#pragma unroll
        for (int i = 0; i < 4; ++i)
#pragma unroll
            for (int q = 0; q < 4; ++q) {
                int ml = rowA0 + wr * 64 + i * 16 + hi * 4 + q;   // local chunk row
                float v = acc[i][j][q] + bs;
                Cg[(size_t)ml * HID + n] = f2b(v);
                if (m0 + ml < NN) { s += v; q2 += v * v; }        // exclude padding rows
            }
        s  += __shfl_down(s, 32);  s  += __shfl_down(s, 16);
        q2 += __shfl_down(q2, 32); q2 += __shfl_down(q2, 16);
        if (lane < 16) { sred[wr][wc][j][l15][0] = s; sred[wr][wc][j][l15][1] = q2; }
    }
    __syncthreads();
    if (t < 128) {   // one thread per block column
        int wcc = t >> 6, j = (t >> 4) & 3, li = t & 15;
        float s  = sred[0][wcc][j][li][0] + sred[1][wcc][j][li][0];
        float q2 = sred[0][wcc][j][li][1] + sred[1][wcc][j][li][1];
        int slot = (m0 >> 7) + bm;          // global 128-row slot, unique per (layer, slot)
        int cg = rowB0 + t;                 // global column 0..255
        partialC[(size_t)slot * 512 + cg] = s;
        partialC[(size_t)slot * 512 + 256 + cg] = q2;
    }
}

// ---------------- BN reduce (deterministic, hierarchical) ----------------
__global__ void bn_red1(const float* __restrict__ pc, float* __restrict__ t2) {
    int b = blockIdx.x;      // 64
    int ch = threadIdx.x;    // 256
    float s0 = 0.f, s1 = 0.f;
    for (int s = b; s < NSLOT; s += 64) {
        s0 += pc[(size_t)s * 512 + ch];
        s1 += pc[(size_t)s * 512 + 256 + ch];
    }
    t2[b * 512 + ch] = s0;
    t2[b * 512 + 256 + ch] = s1;
}

// MUST be launched with exactly HID(=256) threads; guard enforces the contract.
__global__ void bn_fin2(const float* __restrict__ t2, float* __restrict__ mi) {
    int ch = threadIdx.x;
    if (ch >= HID) return;
    float s = 0.f, q2 = 0.f;
    for (int b = 0; b < 64; ++b) {
        s += t2[b * 512 + ch];
        q2 += t2[b * 512 + 256 + ch];
    }
    float mean = s / (float)NN;
    float var = q2 / (float)NN - mean * mean;
    if (var < 0.f) var = 0.f;
    mi[ch] = mean;
    mi[HID + ch] = rsqrtf(var + BN_EPS);
}

// relu(bn(C)) -> bf16 into X2 (stride 256)
__global__ void bn_relu(const unsigned short* __restrict__ Cin, const float* __restrict__ mi,
                        const float* __restrict__ gamma, const float* __restrict__ beta,
                        unsigned short* __restrict__ Xout) {
    int tid = blockIdx.x * 256 + threadIdx.x;  // NN*64 threads (exact)
    int i = tid >> 6;
    int ch = (tid & 63) << 2;
    ushort4 v = *(const ushort4*)(Cin + (size_t)i * HID + ch);
    float vv[4] = { b2f(v.x), b2f(v.y), b2f(v.z), b2f(v.w) };
    ushort4 o;
    unsigned short* op = (unsigned short*)&o;
#pragma unroll
    for (int q = 0; q < 4; ++q) {
        int c = ch + q;
        float y = gamma[c] * (vv[q] - mi[c]) * mi[HID + c] + beta[c];
        op[q] = f2b(fmaxf(y, 0.f));
    }
    *(ushort4*)(Xout + (size_t)i * HID + ch) = o;
}

// fused bn2 + relu + classifier for tx rows: one wave per row
__global__ __launch_bounds__(256) void classify(
    const unsigned short* __restrict__ Cin, const float* __restrict__ mi,
    const float* __restrict__ gamma, const float* __restrict__ beta,
    const float* __restrict__ cw, const float* __restrict__ cb,
    float* __restrict__ out) {
    int w = threadIdx.x >> 6, lane = threadIdx.x & 63;
    int i = blockIdx.x * 4 + w;
    if (i >= NUM_TX) return;
    int ch = lane << 2;
    ushort4 v = *(const ushort4*)(Cin + (size_t)i * HID + ch);
    float vv[4] = { b2f(v.x), b2f(v.y), b2f(v.z), b2f(v.w) };
    float a0 = 0.f, a1 = 0.f;
#pragma unroll
    for (int q = 0; q < 4; ++q) {
        int c = ch + q;
        float y = gamma[c] * (vv[q] - mi[c]) * mi[HID + c] + beta[c];
        y = fmaxf(y, 0.f);
        a0 += y * cw[c * 2 + 0];
        a1 += y * cw[c * 2 + 1];
    }
#pragma unroll
    for (int d = 32; d; d >>= 1) { a0 += __shfl_down(a0, d); a1 += __shfl_down(a1, d); }
    if (lane == 0) {
        out[(size_t)i * 2 + 0] = a0 + cb[0];
        out[(size_t)i * 2 + 1] = a1 + cb[1];
    }
}

// ---------------- launch ----------------
extern "C" void kernel_launch(void* const* d_in, const int* in_sizes, int n_in,
                              void* d_out, int out_size, void* d_ws, size_t ws_size,
                              hipStream_t stream) {
    const float* x_tx   = (const float*)d_in[0];
    const float* ue     = (const float*)d_in[1];
    const float* de     = (const float*)d_in[2];
    const float* relw1  = (const float*)d_in[3];
    const float* rootw1 = (const float*)d_in[4];
    const float* bias1  = (const float*)d_in[5];
    const float* relw2  = (const float*)d_in[6];
    const float* rootw2 = (const float*)d_in[7];
    const float* bias2  = (const float*)d_in[8];
    const float* g1     = (const float*)d_in[9];
    const float* be1    = (const float*)d_in[10];
    const float* g2     = (const float*)d_in[11];
    const float* be2    = (const float*)d_in[12];
    const float* cw     = (const float*)d_in[13];
    const float* cb     = (const float*)d_in[14];
    const int*   ei     = (const int*)d_in[15];
    const int*   et     = (const int*)d_in[16];
    float* out = (float*)d_out;
    (void)in_sizes; (void)n_in;

    // ---- fixed workspace layout (~162 MB) ----
    char* p = (char*)d_ws;
    auto take = [&](size_t b) { char* r = p; p += (b + 255) & ~(size_t)255; return r; };
    unsigned short* X  = (unsigned short*)take((size_t)MP * HID * 2);  // X1 stride 128 / X2 stride 256
    unsigned short* Cb = (unsigned short*)take((size_t)MP * HID * 2);  // pre-BN activations, bf16
    unsigned short* Wt1 = (unsigned short*)take((size_t)HID * 640 * 2);
    unsigned short* Wt2 = (unsigned short*)take((size_t)HID * 1280 * 2);
    int* ecnt  = (int*)take((size_t)NN * 4);
    int* eoff  = (int*)take((size_t)(NN + 1) * 4);
    int* sedge = (int*)take((size_t)NEDGE * 4);
    unsigned long long* ptmp = (unsigned long long*)take((size_t)NEDGE * 8);
    int* pctr  = (int*)take((size_t)NPART * 16 * 4);   // padded: 1 line per counter
    int* bsum  = (int*)take((size_t)SCAN_NB * 4);
    float* partialC = (float*)take((size_t)NSLOT * 512 * 4);
    float* t2red    = (float*)take((size_t)64 * 512 * 4);
    float* mi1 = (float*)take(512 * 4);
    float* mi2 = (float*)take(512 * 4);
    size_t fixed = (size_t)(p - (char*)d_ws);

    // ---- adaptive AGG-chunk: CH rows of [4*256] bf16 (layer2 worst case) ----
    long long rem = (long long)ws_size - (long long)fixed;
    long long chv = rem / (4 * HID * 2);
    int CH = (chv >= 128) ? (int)(chv & ~127LL) : 0;
    if (CH > CH_CAP) CH = CH_CAP;
    if (CH < 128) {
        mark_ws<<<(out_size + 255) / 256, 256, 0, stream>>>(out, out_size, (float)(ws_size >> 20));
        return;
    }
    unsigned short* Achunk = (unsigned short*)take((size_t)CH * 4 * HID * 2);

    hipMemsetAsync(ecnt, 0, (size_t)NN * 4, stream);
    hipMemsetAsync(pctr, 0, (size_t)NPART * 16 * 4, stream);

    count_edges<<<(NEDGE + 255) / 256, 256, 0, stream>>>(ei, ecnt);
    scan_bsum<<<SCAN_NB, 256, 0, stream>>>(ecnt, bsum);
    scan_bscan<<<1, 1024, 0, stream>>>(bsum);
    scan_final<<<SCAN_NB, 256, 0, stream>>>(ecnt, bsum, eoff);
    scatter_part1<<<P1_NB, 256, 0, stream>>>(ei, et, eoff, pctr, ptmp);
    scatter_part2<<<NPART, 1024, 0, stream>>>(eoff, ptmp, sedge);

    build_x0<<<NN * 32 / 256, 256, 0, stream>>>(x_tx, ue, de, X);
    build_wt<<<640, 256, 0, stream>>>(rootw1, relw1, Wt1, 640, 128);
    build_wt<<<1280, 256, 0, stream>>>(rootw2, relw2, Wt2, 1280, 256);

    // ---- layer 1 (C_in = 128, K = 640) ----
    for (int m0 = 0; m0 < MP; m0 += CH) {
        int rows = (MP - m0 < CH) ? (MP - m0) : CH;
        int mb = rows / 128;
        int grid = ((mb * 2 + 15) / 16) * 16;   // round up for the XCD-pair swizzle
        aggregate<128><<<rows / 4, 256, 0, stream>>>(X, Achunk, eoff, sedge, m0);
        gemm_split<128><<<grid, 256, 0, stream>>>(X, Achunk, Wt1, Cb + (size_t)m0 * HID, bias1, partialC, mb, m0);
    }
    bn_red1<<<64, 256, 0, stream>>>(partialC, t2red);
    bn_fin2<<<1, 256, 0, stream>>>(t2red, mi1);
    bn_relu<<<NN * 64 / 256, 256, 0, stream>>>(Cb, mi1, g1, be1, X);

    // ---- layer 2 (C_in = 256, K = 1280) ----
    for (int m0 = 0; m0 < MP; m0 += CH) {
        int rows = (MP - m0 < CH) ? (MP - m0) : CH;
        int mb = rows / 128;
        int grid = ((mb * 2 + 15) / 16) * 16;
        aggregate<256><<<rows / 4, 256, 0, stream>>>(X, Achunk, eoff, sedge, m0);
        gemm_split<256><<<grid, 256, 0, stream>>>(X, Achunk, Wt2, Cb + (size_t)m0 * HID, bias2, partialC, mb, m0);
    }
    bn_red1<<<64, 256, 0, stream>>>(partialC, t2red);
    bn_fin2<<<1, 256, 0, stream>>>(t2red, mi2);
    classify<<<NUM_TX / 4, 256, 0, stream>>>(Cb, mi2, g2, be2, cw, cb, out);
}

// Round 12
// 724.184 us; speedup vs baseline: 1.1862x; 1.1115x over previous
//
#include <hip/hip_runtime.h>
#include <hip/hip_bf16.h>

#define NUM_TX   100000
#define NUM_USER 30000
#define NUM_DEV  10000
#define NN       140000   // total nodes
#define MP       140032   // NN padded to multiple of 128
#define NSLOT    1094     // MP/128 row-block slots
#define INC      128
#define HID      256
#define NEDGE    1000000
#define BN_EPS   1e-5f
#define SCAN_NB  548      // ceil((NN+1)/256)
#define NPART    137      // ceil(NN/1024) dst partitions for 2-pass scatter
#define P1_NB    500      // pass-1 blocks
#define P1_CHUNK 2000     // NEDGE / P1_NB (exact)
#define CH_CAP   35072    // chunk-row cap (multiple of 128): AGG chunk <= 71.8 MB for L3 residency

typedef __attribute__((ext_vector_type(8))) short bf16x8;
typedef __attribute__((ext_vector_type(4))) float f32x4;

__device__ __forceinline__ float b2f(unsigned short s) {
    union { unsigned int u; float f; } c; c.u = ((unsigned int)s) << 16; return c.f;
}
__device__ __forceinline__ unsigned short f2b(float f) {
    union { __hip_bfloat16 h; unsigned short s; } c; c.h = __float2bfloat16(f); return c.s;
}

// ---------------- diagnostic fallback: encode ws_size into the output ----------------
__global__ void mark_ws(float* __restrict__ out, int n, float val) {
    int i = blockIdx.x * 256 + threadIdx.x;
    if (i < n) out[i] = val;
}

// ---------------- edge preprocessing ----------------
__global__ void count_edges(const int* __restrict__ ei, int* __restrict__ cnt) {
    int e = blockIdx.x * 256 + threadIdx.x;
    if (e >= NEDGE) return;
    atomicAdd(&cnt[ei[NEDGE + e]], 1);
}

__global__ void scan_bsum(const int* __restrict__ cnt, int* __restrict__ bsum) {
    int t = threadIdx.x;
    int i = blockIdx.x * 256 + t;
    int v = (i < NN) ? cnt[i] : 0;
    __shared__ int ls[4];
#pragma unroll
    for (int d = 32; d; d >>= 1) v += __shfl_down(v, d);
    if ((t & 63) == 0) ls[t >> 6] = v;
    __syncthreads();
    if (t == 0) bsum[blockIdx.x] = ls[0] + ls[1] + ls[2] + ls[3];
}

__global__ void scan_bscan(int* __restrict__ bsum) {
    __shared__ int ss[1024];
    int t = threadIdx.x;
    int v = (t < SCAN_NB) ? bsum[t] : 0;
    ss[t] = v;
    __syncthreads();
    for (int d = 1; d < 1024; d <<= 1) {
        int u = (t >= d) ? ss[t - d] : 0;
        __syncthreads();
        ss[t] += u;
        __syncthreads();
    }
    if (t < SCAN_NB) bsum[t] = ss[t] - v;   // exclusive
}

__global__ void scan_final(const int* __restrict__ cnt, const int* __restrict__ bsum,
                           int* __restrict__ off) {
    __shared__ int ss[256];
    int t = threadIdx.x;
    int i = blockIdx.x * 256 + t;
    int v = (i < NN) ? cnt[i] : 0;
    ss[t] = v;
    __syncthreads();
    for (int d = 1; d < 256; d <<= 1) {
        int u = (t >= d) ? ss[t - d] : 0;
        __syncthreads();
        ss[t] += u;
        __syncthreads();
    }
    if (i <= NN) off[i] = bsum[blockIdx.x] + ss[t] - v;
}

// ---- 2-pass partition scatter (WRITE_SIZE 73->8.3 MB r10; occupancy fixed r11) ----
__global__ __launch_bounds__(256) void scatter_part1(
    const int* __restrict__ ei, const int* __restrict__ et,
    const int* __restrict__ eoff, int* __restrict__ pctr,
    unsigned long long* __restrict__ ptmp) {
    __shared__ int hist[NPART];
    __shared__ int base[NPART];
    __shared__ int runc[NPART];
    int b = blockIdx.x, t = threadIdx.x;
    int e0 = b * P1_CHUNK, e1 = e0 + P1_CHUNK;
    for (int i = t; i < NPART; i += 256) { hist[i] = 0; runc[i] = 0; }
    __syncthreads();
    for (int e = e0 + t; e < e1; e += 256)
        atomicAdd(&hist[ei[NEDGE + e] >> 10], 1);
    __syncthreads();
    if (t < NPART)
        base[t] = eoff[t << 10] + atomicAdd(&pctr[t * 16], hist[t]);  // padded counters: 1 line each
    __syncthreads();
    for (int e = e0 + t; e < e1; e += 256) {
        int dst = ei[NEDGE + e];
        int p = dst >> 10;
        int r = atomicAdd(&runc[p], 1);
        unsigned long long w = (unsigned long long)(unsigned)ei[e]
                             | ((unsigned long long)(unsigned)et[e] << 18)
                             | ((unsigned long long)(unsigned)dst << 20);
        ptmp[(size_t)base[p] + r] = w;
    }
}

__global__ __launch_bounds__(1024) void scatter_part2(
    const int* __restrict__ eoff, const unsigned long long* __restrict__ ptmp,
    int* __restrict__ sedge) {
    __shared__ int lctr[1024];
    int p = blockIdx.x, t = threadIdx.x;
    int n0 = p << 10;
    int n1 = n0 + 1024; if (n1 > NN) n1 = NN;
    lctr[t] = 0;
    __syncthreads();
    int lo = eoff[n0], hi = eoff[n1];
    for (int j = lo + t; j < hi; j += 1024) {
        unsigned long long w = ptmp[j];
        int src = (int)(w & 0x3FFFF);
        int rel = (int)((w >> 18) & 3);
        int dst = (int)(w >> 20);
        int r = atomicAdd(&lctr[dst - n0], 1);
        sedge[eoff[dst] + r] = src | (rel << 28);
    }
}

// ---------------- input / weight staging ----------------
__global__ void build_x0(const float* __restrict__ xt, const float* __restrict__ ue,
                         const float* __restrict__ de, unsigned short* __restrict__ X) {
    int tid = blockIdx.x * 256 + threadIdx.x;   // NN*32 threads (exact)
    int i = tid >> 5;
    int c4 = (tid & 31) << 2;
    const float* s;
    if (i < NUM_TX) s = xt + (size_t)i * INC;
    else if (i < NUM_TX + NUM_USER) s = ue + (size_t)(i - NUM_TX) * INC;
    else s = de + (size_t)(i - NUM_TX - NUM_USER) * INC;
    float4 v = *(const float4*)(s + c4);
    ushort4 o;
    o.x = f2b(v.x); o.y = f2b(v.y); o.z = f2b(v.z); o.w = f2b(v.w);
    *(ushort4*)(X + (size_t)i * INC + c4) = o;
}

// Wt[n*K + k] = bf16( k<rootK ? root[k][n] : rel[(k-rootK)][n] )  (n-major for GEMM B^T)
__global__ void build_wt(const float* __restrict__ rootw, const float* __restrict__ relw,
                         unsigned short* __restrict__ Wt, int K, int rootK) {
    int tid = blockIdx.x * 256 + threadIdx.x;   // 256*K threads (grid = K blocks, exact)
    int n = tid / K, k = tid - n * K;
    float v = (k < rootK) ? rootw[(size_t)k * HID + n] : relw[(size_t)(k - rootK) * HID + n];
    Wt[tid] = f2b(v);
}

// ---------------- segmented mean aggregation (all 4 relations, one edge walk) ----------------
template<int C>
__global__ __launch_bounds__(256) void aggregate(
    const unsigned short* __restrict__ X, unsigned short* __restrict__ AGG,
    const int* __restrict__ eoff, const int* __restrict__ sedge, int m0) {
    constexpr int V = C / 64;
    int w = threadIdx.x >> 6, lane = threadIdx.x & 63;
    int i = m0 + blockIdx.x * 4 + w;
    if (i >= NN) return;
    float a0[V] = {}, a1[V] = {}, a2[V] = {}, a3[V] = {};
    int c0 = 0, c1 = 0, c2 = 0, c3 = 0;
    int b = eoff[i], e = eoff[i + 1];
    for (int p = b; p < e; ++p) {
        int pe = sedge[p];                 // wave-uniform
        int src = pe & 0x0FFFFFFF;
        int r = pe >> 28;
        const unsigned short* row = X + (size_t)src * C + lane * V;
        float v[V];
        if constexpr (V == 2) {
            unsigned int u = *(const unsigned int*)row;
            v[0] = b2f((unsigned short)(u & 0xFFFF));
            v[1] = b2f((unsigned short)(u >> 16));
        } else {
            ushort4 u = *(const ushort4*)row;
            v[0] = b2f(u.x); v[1] = b2f(u.y); v[2] = b2f(u.z); v[3] = b2f(u.w);
        }
        switch (r) {                       // wave-uniform branch
            case 0:  { for (int j = 0; j < V; ++j) a0[j] += v[j]; c0++; } break;
            case 1:  { for (int j = 0; j < V; ++j) a1[j] += v[j]; c1++; } break;
            case 2:  { for (int j = 0; j < V; ++j) a2[j] += v[j]; c2++; } break;
            default: { for (int j = 0; j < V; ++j) a3[j] += v[j]; c3++; } break;
        }
    }
    float s0 = 1.0f / (float)(c0 > 1 ? c0 : 1);
    float s1 = 1.0f / (float)(c1 > 1 ? c1 : 1);
    float s2 = 1.0f / (float)(c2 > 1 ? c2 : 1);
    float s3 = 1.0f / (float)(c3 > 1 ? c3 : 1);
    unsigned short* orow = AGG + (size_t)(i - m0) * (4 * C) + lane * V;
#pragma unroll
    for (int j = 0; j < V; ++j) {
        orow[0 * C + j] = f2b(a0[j] * s0);
        orow[1 * C + j] = f2b(a1[j] * s1);
        orow[2 * C + j] = f2b(a2[j] * s2);
        orow[3 * C + j] = f2b(a3[j] * s3);
    }
}

// ---------------- bf16 MFMA GEMM ----------------
// r12: single-buffer m97-style loop (33KB LDS -> 4 blocks/CU; r11's explicit dbuf at
// 66KB capped residency at 2 blocks/CU and sat latency-bound at MfmaUtil 16%).
// Keeps: split-source A, XOR-swizzled LDS (conflicts=0, r11), XCD-pairing, fused BN.
template<int C>
__global__ __launch_bounds__(256) void gemm_split(
    const unsigned short* __restrict__ Xg, const unsigned short* __restrict__ AGGg,
    const unsigned short* __restrict__ Wt, unsigned short* __restrict__ Cg,
    const float* __restrict__ bias, float* __restrict__ partialC, int mblocks, int m0) {
    constexpr int K = 5 * C;
    constexpr int NKT = K / 64;
    constexpr int XKT = C / 64;
    __shared__ unsigned short As[128 * 64];
    __shared__ unsigned short Bs[128 * 64];
    __shared__ float sred[2][2][4][16][2];   // [wr][wc][j][l15][{s,s2}]
    int bid = blockIdx.x;
    int bm = (bid & 7) + ((bid >> 4) << 3);
    int bn = (bid >> 3) & 1;
    if (bm >= mblocks) return;               // pad blocks from grid round-up
    int t = threadIdx.x;
    int lane = t & 63, w = t >> 6;
    int wr = w >> 1, wc = w & 1;
    int l15 = lane & 15, l7 = lane & 7, hi = lane >> 4;
    f32x4 acc[4][4] = {};
    const int rowA0 = bm * 128, rowB0 = bn * 128;

    auto STAGE = [&](int kt) {
#pragma unroll
        for (int it = 0; it < 4; ++it) {
            int R = it * 32 + (t >> 3);
            int sl = (t & 7) ^ (R & 7);           // pre-swizzled global slot
            const unsigned short* ga;
            if (kt < XKT)
                ga = Xg + (size_t)(m0 + rowA0 + R) * C + kt * 64 + sl * 8;
            else
                ga = AGGg + (size_t)(rowA0 + R) * (4 * C) + (kt - XKT) * 64 + sl * 8;
            __builtin_amdgcn_global_load_lds(
                (const __attribute__((address_space(1))) void*)ga,
                (__attribute__((address_space(3))) void*)(As + it * 2048 + t * 8), 16, 0, 0);
            const unsigned short* gb = Wt + (size_t)(rowB0 + R) * K + kt * 64 + sl * 8;
            __builtin_amdgcn_global_load_lds(
                (const __attribute__((address_space(1))) void*)gb,
                (__attribute__((address_space(3))) void*)(Bs + it * 2048 + t * 8), 16, 0, 0);
        }
    };

    for (int kt = 0; kt < NKT; ++kt) {
        STAGE(kt);
        asm volatile("s_waitcnt vmcnt(0)" ::: "memory");
        __builtin_amdgcn_s_barrier();
        __builtin_amdgcn_sched_barrier(0);
#pragma unroll
        for (int kk = 0; kk < 64; kk += 32) {
            bf16x8 af[4], bfr[4];
            int sl2 = (((kk >> 3) + hi) ^ l7) << 3;
#pragma unroll
            for (int f = 0; f < 4; ++f) {
                int m = wr * 64 + f * 16 + l15;
                af[f] = *(const bf16x8*)(As + m * 64 + sl2);
                int n = wc * 64 + f * 16 + l15;
                bfr[f] = *(const bf16x8*)(Bs + n * 64 + sl2);
            }
#pragma unroll
            for (int i = 0; i < 4; ++i)
#pragma unroll
                for (int j = 0; j < 4; ++j)
                    acc[i][j] = __builtin_amdgcn_mfma_f32_16x16x32_bf16(af[i], bfr[j], acc[i][j], 0, 0, 0);
        }
        __builtin_amdgcn_s_barrier();        // all waves done reading before next STAGE overwrites
        __builtin_amdgcn_sched_barrier(0);
    }

    // ---- epilogue: C-write + fused BN partial sums ----
#pragma unroll
    for (int j = 0; j < 4; ++j) {
        int n = rowB0 + wc * 64 + j * 16 + l15;
        float bs = bias[n];
        float s = 0.f, q2 = 0.f;
#pragma unroll
        for (int i = 0; i < 4; ++i)
#pragma unroll
            for (int q = 0; q < 4; ++q) {
                int ml = rowA0 + wr * 64 + i * 16 + hi * 4 + q;   // local chunk row
                float v = acc[i][j][q] + bs;
                Cg[(size_t)ml * HID + n] = f2b(v);
                if (m0 + ml < NN) { s += v; q2 += v * v; }        // exclude padding rows
            }
        s  += __shfl_down(s, 32);  s  += __shfl_down(s, 16);
        q2 += __shfl_down(q2, 32); q2 += __shfl_down(q2, 16);
        if (lane < 16) { sred[wr][wc][j][l15][0] = s; sred[wr][wc][j][l15][1] = q2; }
    }
    __syncthreads();
    if (t < 128) {   // one thread per block column
        int wcc = t >> 6, j = (t >> 4) & 3, li = t & 15;
        float s  = sred[0][wcc][j][li][0] + sred[1][wcc][j][li][0];
        float q2 = sred[0][wcc][j][li][1] + sred[1][wcc][j][li][1];
        int slot = (m0 >> 7) + bm;          // global 128-row slot, unique per (layer, slot)
        int cg = rowB0 + t;                 // global column 0..255
        partialC[(size_t)slot * 512 + cg] = s;
        partialC[(size_t)slot * 512 + 256 + cg] = q2;
    }
}

// ---------------- BN reduce (deterministic, hierarchical) ----------------
__global__ void bn_red1(const float* __restrict__ pc, float* __restrict__ t2) {
    int b = blockIdx.x;      // 64
    int ch = threadIdx.x;    // 256
    float s0 = 0.f, s1 = 0.f;
    for (int s = b; s < NSLOT; s += 64) {
        s0 += pc[(size_t)s * 512 + ch];
        s1 += pc[(size_t)s * 512 + 256 + ch];
    }
    t2[b * 512 + ch] = s0;
    t2[b * 512 + 256 + ch] = s1;
}

// MUST be launched with exactly HID(=256) threads; guard enforces the contract.
__global__ void bn_fin2(const float* __restrict__ t2, float* __restrict__ mi) {
    int ch = threadIdx.x;
    if (ch >= HID) return;
    float s = 0.f, q2 = 0.f;
    for (int b = 0; b < 64; ++b) {
        s += t2[b * 512 + ch];
        q2 += t2[b * 512 + 256 + ch];
    }
    float mean = s / (float)NN;
    float var = q2 / (float)NN - mean * mean;
    if (var < 0.f) var = 0.f;
    mi[ch] = mean;
    mi[HID + ch] = rsqrtf(var + BN_EPS);
}

// relu(bn(C)) -> bf16 into X2 (stride 256)
__global__ void bn_relu(const unsigned short* __restrict__ Cin, const float* __restrict__ mi,
                        const float* __restrict__ gamma, const float* __restrict__ beta,
                        unsigned short* __restrict__ Xout) {
    int tid = blockIdx.x * 256 + threadIdx.x;  // NN*64 threads (exact)
    int i = tid >> 6;
    int ch = (tid & 63) << 2;
    ushort4 v = *(const ushort4*)(Cin + (size_t)i * HID + ch);
    float vv[4] = { b2f(v.x), b2f(v.y), b2f(v.z), b2f(v.w) };
    ushort4 o;
    unsigned short* op = (unsigned short*)&o;
#pragma unroll
    for (int q = 0; q < 4; ++q) {
        int c = ch + q;
        float y = gamma[c] * (vv[q] - mi[c]) * mi[HID + c] + beta[c];
        op[q] = f2b(fmaxf(y, 0.f));
    }
    *(ushort4*)(Xout + (size_t)i * HID + ch) = o;
}

// fused bn2 + relu + classifier for tx rows: one wave per row
__global__ __launch_bounds__(256) void classify(
    const unsigned short* __restrict__ Cin, const float* __restrict__ mi,
    const float* __restrict__ gamma, const float* __restrict__ beta,
    const float* __restrict__ cw, const float* __restrict__ cb,
    float* __restrict__ out) {
    int w = threadIdx.x >> 6, lane = threadIdx.x & 63;
    int i = blockIdx.x * 4 + w;
    if (i >= NUM_TX) return;
    int ch = lane << 2;
    ushort4 v = *(const ushort4*)(Cin + (size_t)i * HID + ch);
    float vv[4] = { b2f(v.x), b2f(v.y), b2f(v.z), b2f(v.w) };
    float a0 = 0.f, a1 = 0.f;
#pragma unroll
    for (int q = 0; q < 4; ++q) {
        int c = ch + q;
        float y = gamma[c] * (vv[q] - mi[c]) * mi[HID + c] + beta[c];
        y = fmaxf(y, 0.f);
        a0 += y * cw[c * 2 + 0];
        a1 += y * cw[c * 2 + 1];
    }
#pragma unroll
    for (int d = 32; d; d >>= 1) { a0 += __shfl_down(a0, d); a1 += __shfl_down(a1, d); }
    if (lane == 0) {
        out[(size_t)i * 2 + 0] = a0 + cb[0];
        out[(size_t)i * 2 + 1] = a1 + cb[1];
    }
}

// ---------------- launch ----------------
extern "C" void kernel_launch(void* const* d_in, const int* in_sizes, int n_in,
                              void* d_out, int out_size, void* d_ws, size_t ws_size,
                              hipStream_t stream) {
    const float* x_tx   = (const float*)d_in[0];
    const float* ue     = (const float*)d_in[1];
    const float* de     = (const float*)d_in[2];
    const float* relw1  = (const float*)d_in[3];
    const float* rootw1 = (const float*)d_in[4];
    const float* bias1  = (const float*)d_in[5];
    const float* relw2  = (const float*)d_in[6];
    const float* rootw2 = (const float*)d_in[7];
    const float* bias2  = (const float*)d_in[8];
    const float* g1     = (const float*)d_in[9];
    const float* be1    = (const float*)d_in[10];
    const float* g2     = (const float*)d_in[11];
    const float* be2    = (const float*)d_in[12];
    const float* cw     = (const float*)d_in[13];
    const float* cb     = (const float*)d_in[14];
    const int*   ei     = (const int*)d_in[15];
    const int*   et     = (const int*)d_in[16];
    float* out = (float*)d_out;
    (void)in_sizes; (void)n_in;

    // ---- fixed workspace layout (~162 MB) ----
    char* p = (char*)d_ws;
    auto take = [&](size_t b) { char* r = p; p += (b + 255) & ~(size_t)255; return r; };
    unsigned short* X  = (unsigned short*)take((size_t)MP * HID * 2);  // X1 stride 128 / X2 stride 256
    unsigned short* Cb = (unsigned short*)take((size_t)MP * HID * 2);  // pre-BN activations, bf16
    unsigned short* Wt1 = (unsigned short*)take((size_t)HID * 640 * 2);
    unsigned short* Wt2 = (unsigned short*)take((size_t)HID * 1280 * 2);
    int* ecnt  = (int*)take((size_t)NN * 4);
    int* eoff  = (int*)take((size_t)(NN + 1) * 4);
    int* sedge = (int*)take((size_t)NEDGE * 4);
    unsigned long long* ptmp = (unsigned long long*)take((size_t)NEDGE * 8);
    int* pctr  = (int*)take((size_t)NPART * 16 * 4);   // padded: 1 line per counter
    int* bsum  = (int*)take((size_t)SCAN_NB * 4);
    float* partialC = (float*)take((size_t)NSLOT * 512 * 4);
    float* t2red    = (float*)take((size_t)64 * 512 * 4);
    float* mi1 = (float*)take(512 * 4);
    float* mi2 = (float*)take(512 * 4);
    size_t fixed = (size_t)(p - (char*)d_ws);

    // ---- adaptive AGG-chunk: CH rows of [4*256] bf16 (layer2 worst case) ----
    long long rem = (long long)ws_size - (long long)fixed;
    long long chv = rem / (4 * HID * 2);
    int CH = (chv >= 128) ? (int)(chv & ~127LL) : 0;
    if (CH > CH_CAP) CH = CH_CAP;
    if (CH < 128) {
        mark_ws<<<(out_size + 255) / 256, 256, 0, stream>>>(out, out_size, (float)(ws_size >> 20));
        return;
    }
    unsigned short* Achunk = (unsigned short*)take((size_t)CH * 4 * HID * 2);

    hipMemsetAsync(ecnt, 0, (size_t)NN * 4, stream);
    hipMemsetAsync(pctr, 0, (size_t)NPART * 16 * 4, stream);

    count_edges<<<(NEDGE + 255) / 256, 256, 0, stream>>>(ei, ecnt);
    scan_bsum<<<SCAN_NB, 256, 0, stream>>>(ecnt, bsum);
    scan_bscan<<<1, 1024, 0, stream>>>(bsum);
    scan_final<<<SCAN_NB, 256, 0, stream>>>(ecnt, bsum, eoff);
    scatter_part1<<<P1_NB, 256, 0, stream>>>(ei, et, eoff, pctr, ptmp);
    scatter_part2<<<NPART, 1024, 0, stream>>>(eoff, ptmp, sedge);

    build_x0<<<NN * 32 / 256, 256, 0, stream>>>(x_tx, ue, de, X);
    build_wt<<<640, 256, 0, stream>>>(rootw1, relw1, Wt1, 640, 128);
    build_wt<<<1280, 256, 0, stream>>>(rootw2, relw2, Wt2, 1280, 256);

    // ---- layer 1 (C_in = 128, K = 640) ----
    for (int m0 = 0; m0 < MP; m0 += CH) {
        int rows = (MP - m0 < CH) ? (MP - m0) : CH;
        int mb = rows / 128;
        int grid = ((mb * 2 + 15) / 16) * 16;   // round up for the XCD-pair swizzle
        aggregate<128><<<rows / 4, 256, 0, stream>>>(X, Achunk, eoff, sedge, m0);
        gemm_split<128><<<grid, 256, 0, stream>>>(X, Achunk, Wt1, Cb + (size_t)m0 * HID, bias1, partialC, mb, m0);
    }
    bn_red1<<<64, 256, 0, stream>>>(partialC, t2red);
    bn_fin2<<<1, 256, 0, stream>>>(t2red, mi1);
    bn_relu<<<NN * 64 / 256, 256, 0, stream>>>(Cb, mi1, g1, be1, X);

    // ---- layer 2 (C_in = 256, K = 1280) ----
    for (int m0 = 0; m0 < MP; m0 += CH) {
        int rows = (MP - m0 < CH) ? (MP - m0) : CH;
        int mb = rows / 128;
        int grid = ((mb * 2 + 15) / 16) * 16;
        aggregate<256><<<rows / 4, 256, 0, stream>>>(X, Achunk, eoff, sedge, m0);
        gemm_split<256><<<grid, 256, 0, stream>>>(X, Achunk, Wt2, Cb + (size_t)m0 * HID, bias2, partialC, mb, m0);
    }
    bn_red1<<<64, 256, 0, stream>>>(partialC, t2red);
    bn_fin2<<<1, 256, 0, stream>>>(t2red, mi2);
    classify<<<NUM_TX / 4, 256, 0, stream>>>(Cb, mi2, g2, be2, cw, cb, out);
}

// Round 13
// 651.008 us; speedup vs baseline: 1.3196x; 1.1124x over previous
//
#include <hip/hip_runtime.h>
#include <hip/hip_bf16.h>

#define NUM_TX   100000
#define NUM_USER 30000
#define NUM_DEV  10000
#define NN       140000   // total nodes
#define MP       140032   // NN padded to multiple of 128
#define NSLOT    1094     // MP/128 row-block slots
#define INC      128
#define HID      256
#define NEDGE    1000000
#define BN_EPS   1e-5f
#define SCAN_NB  548      // ceil((NN+1)/256)
#define NPART    137      // ceil(NN/1024) dst partitions for 2-pass scatter
#define P1_NB    500      // pass-1 blocks
#define P1_CHUNK 2000     // NEDGE / P1_NB (exact)
#define CH_CAP   35072    // chunk-row cap (multiple of 128): AGG chunk <= 71.8 MB for L3 residency

typedef __attribute__((ext_vector_type(8))) short bf16x8;
typedef __attribute__((ext_vector_type(4))) float f32x4;

__device__ __forceinline__ float b2f(unsigned short s) {
    union { unsigned int u; float f; } c; c.u = ((unsigned int)s) << 16; return c.f;
}
__device__ __forceinline__ unsigned short f2b(float f) {
    union { __hip_bfloat16 h; unsigned short s; } c; c.h = __float2bfloat16(f); return c.s;
}

// ---------------- diagnostic fallback: encode ws_size into the output ----------------
__global__ void mark_ws(float* __restrict__ out, int n, float val) {
    int i = blockIdx.x * 256 + threadIdx.x;
    if (i < n) out[i] = val;
}

// ---------------- edge preprocessing ----------------
__global__ void count_edges(const int* __restrict__ ei, int* __restrict__ cnt) {
    int e = blockIdx.x * 256 + threadIdx.x;
    if (e >= NEDGE) return;
    atomicAdd(&cnt[ei[NEDGE + e]], 1);
}

__global__ void scan_bsum(const int* __restrict__ cnt, int* __restrict__ bsum) {
    int t = threadIdx.x;
    int i = blockIdx.x * 256 + t;
    int v = (i < NN) ? cnt[i] : 0;
    __shared__ int ls[4];
#pragma unroll
    for (int d = 32; d; d >>= 1) v += __shfl_down(v, d);
    if ((t & 63) == 0) ls[t >> 6] = v;
    __syncthreads();
    if (t == 0) bsum[blockIdx.x] = ls[0] + ls[1] + ls[2] + ls[3];
}

__global__ void scan_bscan(int* __restrict__ bsum) {
    __shared__ int ss[1024];
    int t = threadIdx.x;
    int v = (t < SCAN_NB) ? bsum[t] : 0;
    ss[t] = v;
    __syncthreads();
    for (int d = 1; d < 1024; d <<= 1) {
        int u = (t >= d) ? ss[t - d] : 0;
        __syncthreads();
        ss[t] += u;
        __syncthreads();
    }
    if (t < SCAN_NB) bsum[t] = ss[t] - v;   // exclusive
}

__global__ void scan_final(const int* __restrict__ cnt, const int* __restrict__ bsum,
                           int* __restrict__ off) {
    __shared__ int ss[256];
    int t = threadIdx.x;
    int i = blockIdx.x * 256 + t;
    int v = (i < NN) ? cnt[i] : 0;
    ss[t] = v;
    __syncthreads();
    for (int d = 1; d < 256; d <<= 1) {
        int u = (t >= d) ? ss[t - d] : 0;
        __syncthreads();
        ss[t] += u;
        __syncthreads();
    }
    if (i <= NN) off[i] = bsum[blockIdx.x] + ss[t] - v;
}

// ---- 2-pass partition scatter (WRITE_SIZE 73->8.3 MB r10; occupancy fixed r11) ----
__global__ __launch_bounds__(256) void scatter_part1(
    const int* __restrict__ ei, const int* __restrict__ et,
    const int* __restrict__ eoff, int* __restrict__ pctr,
    unsigned long long* __restrict__ ptmp) {
    __shared__ int hist[NPART];
    __shared__ int base[NPART];
    __shared__ int runc[NPART];
    int b = blockIdx.x, t = threadIdx.x;
    int e0 = b * P1_CHUNK, e1 = e0 + P1_CHUNK;
    for (int i = t; i < NPART; i += 256) { hist[i] = 0; runc[i] = 0; }
    __syncthreads();
    for (int e = e0 + t; e < e1; e += 256)
        atomicAdd(&hist[ei[NEDGE + e] >> 10], 1);
    __syncthreads();
    if (t < NPART)
        base[t] = eoff[t << 10] + atomicAdd(&pctr[t * 16], hist[t]);  // padded counters: 1 line each
    __syncthreads();
    for (int e = e0 + t; e < e1; e += 256) {
        int dst = ei[NEDGE + e];
        int p = dst >> 10;
        int r = atomicAdd(&runc[p], 1);
        unsigned long long w = (unsigned long long)(unsigned)ei[e]
                             | ((unsigned long long)(unsigned)et[e] << 18)
                             | ((unsigned long long)(unsigned)dst << 20);
        ptmp[(size_t)base[p] + r] = w;
    }
}

__global__ __launch_bounds__(1024) void scatter_part2(
    const int* __restrict__ eoff, const unsigned long long* __restrict__ ptmp,
    int* __restrict__ sedge) {
    __shared__ int lctr[1024];
    int p = blockIdx.x, t = threadIdx.x;
    int n0 = p << 10;
    int n1 = n0 + 1024; if (n1 > NN) n1 = NN;
    lctr[t] = 0;
    __syncthreads();
    int lo = eoff[n0], hi = eoff[n1];
    for (int j = lo + t; j < hi; j += 1024) {
        unsigned long long w = ptmp[j];
        int src = (int)(w & 0x3FFFF);
        int rel = (int)((w >> 18) & 3);
        int dst = (int)(w >> 20);
        int r = atomicAdd(&lctr[dst - n0], 1);
        sedge[eoff[dst] + r] = src | (rel << 28);
    }
}

// ---------------- input / weight staging ----------------
__global__ void build_x0(const float* __restrict__ xt, const float* __restrict__ ue,
                         const float* __restrict__ de, unsigned short* __restrict__ X) {
    int tid = blockIdx.x * 256 + threadIdx.x;   // NN*32 threads (exact)
    int i = tid >> 5;
    int c4 = (tid & 31) << 2;
    const float* s;
    if (i < NUM_TX) s = xt + (size_t)i * INC;
    else if (i < NUM_TX + NUM_USER) s = ue + (size_t)(i - NUM_TX) * INC;
    else s = de + (size_t)(i - NUM_TX - NUM_USER) * INC;
    float4 v = *(const float4*)(s + c4);
    ushort4 o;
    o.x = f2b(v.x); o.y = f2b(v.y); o.z = f2b(v.z); o.w = f2b(v.w);
    *(ushort4*)(X + (size_t)i * INC + c4) = o;
}

// Wt[n*K + k] = bf16( k<rootK ? root[k][n] : rel[(k-rootK)][n] )  (n-major for GEMM B^T)
__global__ void build_wt(const float* __restrict__ rootw, const float* __restrict__ relw,
                         unsigned short* __restrict__ Wt, int K, int rootK) {
    int tid = blockIdx.x * 256 + threadIdx.x;   // 256*K threads (grid = K blocks, exact)
    int n = tid / K, k = tid - n * K;
    float v = (k < rootK) ? rootw[(size_t)k * HID + n] : relw[(size_t)(k - rootK) * HID + n];
    Wt[tid] = f2b(v);
}

// ---------------- segmented mean aggregation (all 4 relations, one edge walk) ----------------
// r13: scalarized edge walk. Batch-load 64 edge words per lane (coalesced), broadcast
// each via readlane -> SGPR; relation branch becomes s_cbranch (uniform, one body runs),
// gather uses SGPR base + loop-invariant lane offset. r12 PMC showed VALUBusy 57% from
// the compiler treating r/src as divergent (exec-masked switch + per-lane 64b addressing).
template<int C>
__global__ __launch_bounds__(256) void aggregate(
    const unsigned short* __restrict__ X, unsigned short* __restrict__ AGG,
    const int* __restrict__ eoff, const int* __restrict__ sedge, int m0) {
    constexpr int V = C / 64;
    int w = threadIdx.x >> 6, lane = threadIdx.x & 63;
    int i = m0 + blockIdx.x * 4 + w;
    if (i >= NN) return;
    float a0[V] = {}, a1[V] = {}, a2[V] = {}, a3[V] = {};
    int c0 = 0, c1 = 0, c2 = 0, c3 = 0;
    int b = eoff[i], e = eoff[i + 1];
    const unsigned short* Xl = X + (size_t)lane * V;   // lane offset folded once
    for (int p0 = b; p0 < e; p0 += 64) {
        int nb = e - p0; if (nb > 64) nb = 64;
        int myedge = (p0 + lane < e) ? sedge[p0 + lane] : 0;   // coalesced batch load
        for (int q = 0; q < nb; ++q) {
            int pe = __builtin_amdgcn_readlane(myedge, q);     // SGPR: uniform proven
            int src = pe & 0x0FFFFFFF;
            int r = pe >> 28;
            const unsigned short* row = Xl + (size_t)src * C;
            float v[V];
            if constexpr (V == 2) {
                unsigned int u = *(const unsigned int*)row;
                v[0] = b2f((unsigned short)(u & 0xFFFF));
                v[1] = b2f((unsigned short)(u >> 16));
            } else {
                ushort4 u = *(const ushort4*)row;
                v[0] = b2f(u.x); v[1] = b2f(u.y); v[2] = b2f(u.z); v[3] = b2f(u.w);
            }
            if (r == 0)      { for (int j = 0; j < V; ++j) a0[j] += v[j]; c0++; }
            else if (r == 1) { for (int j = 0; j < V; ++j) a1[j] += v[j]; c1++; }
            else if (r == 2) { for (int j = 0; j < V; ++j) a2[j] += v[j]; c2++; }
            else             { for (int j = 0; j < V; ++j) a3[j] += v[j]; c3++; }
        }
    }
    float s0 = 1.0f / (float)(c0 > 1 ? c0 : 1);
    float s1 = 1.0f / (float)(c1 > 1 ? c1 : 1);
    float s2 = 1.0f / (float)(c2 > 1 ? c2 : 1);
    float s3 = 1.0f / (float)(c3 > 1 ? c3 : 1);
    unsigned short* orow = AGG + (size_t)(i - m0) * (4 * C) + lane * V;
#pragma unroll
    for (int j = 0; j < V; ++j) {
        orow[0 * C + j] = f2b(a0[j] * s0);
        orow[1 * C + j] = f2b(a1[j] * s1);
        orow[2 * C + j] = f2b(a2[j] * s2);
        orow[3 * C + j] = f2b(a3[j] * s3);
    }
}

// ---------------- bf16 MFMA GEMM (single-buffer m97-style, r12 win) ----------------
// Keeps: split-source A, XOR-swizzled LDS (conflicts=0), XCD-pairing, fused BN.
template<int C>
__global__ __launch_bounds__(256) void gemm_split(
    const unsigned short* __restrict__ Xg, const unsigned short* __restrict__ AGGg,
    const unsigned short* __restrict__ Wt, unsigned short* __restrict__ Cg,
    const float* __restrict__ bias, float* __restrict__ partialC, int mblocks, int m0) {
    constexpr int K = 5 * C;
    constexpr int NKT = K / 64;
    constexpr int XKT = C / 64;
    __shared__ unsigned short As[128 * 64];
    __shared__ unsigned short Bs[128 * 64];
    __shared__ float sred[2][2][4][16][2];   // [wr][wc][j][l15][{s,s2}]
    int bid = blockIdx.x;
    int bm = (bid & 7) + ((bid >> 4) << 3);
    int bn = (bid >> 3) & 1;
    if (bm >= mblocks) return;               // pad blocks from grid round-up
    int t = threadIdx.x;
    int lane = t & 63, w = t >> 6;
    int wr = w >> 1, wc = w & 1;
    int l15 = lane & 15, l7 = lane & 7, hi = lane >> 4;
    f32x4 acc[4][4] = {};
    const int rowA0 = bm * 128, rowB0 = bn * 128;

    auto STAGE = [&](int kt) {
#pragma unroll
        for (int it = 0; it < 4; ++it) {
            int R = it * 32 + (t >> 3);
            int sl = (t & 7) ^ (R & 7);           // pre-swizzled global slot
            const unsigned short* ga;
            if (kt < XKT)
                ga = Xg + (size_t)(m0 + rowA0 + R) * C + kt * 64 + sl * 8;
            else
                ga = AGGg + (size_t)(rowA0 + R) * (4 * C) + (kt - XKT) * 64 + sl * 8;
            __builtin_amdgcn_global_load_lds(
                (const __attribute__((address_space(1))) void*)ga,
                (__attribute__((address_space(3))) void*)(As + it * 2048 + t * 8), 16, 0, 0);
            const unsigned short* gb = Wt + (size_t)(rowB0 + R) * K + kt * 64 + sl * 8;
            __builtin_amdgcn_global_load_lds(
                (const __attribute__((address_space(1))) void*)gb,
                (__attribute__((address_space(3))) void*)(Bs + it * 2048 + t * 8), 16, 0, 0);
        }
    };

    for (int kt = 0; kt < NKT; ++kt) {
        STAGE(kt);
        asm volatile("s_waitcnt vmcnt(0)" ::: "memory");
        __builtin_amdgcn_s_barrier();
        __builtin_amdgcn_sched_barrier(0);
#pragma unroll
        for (int kk = 0; kk < 64; kk += 32) {
            bf16x8 af[4], bfr[4];
            int sl2 = (((kk >> 3) + hi) ^ l7) << 3;
#pragma unroll
            for (int f = 0; f < 4; ++f) {
                int m = wr * 64 + f * 16 + l15;
                af[f] = *(const bf16x8*)(As + m * 64 + sl2);
                int n = wc * 64 + f * 16 + l15;
                bfr[f] = *(const bf16x8*)(Bs + n * 64 + sl2);
            }
#pragma unroll
            for (int i = 0; i < 4; ++i)
#pragma unroll
                for (int j = 0; j < 4; ++j)
                    acc[i][j] = __builtin_amdgcn_mfma_f32_16x16x32_bf16(af[i], bfr[j], acc[i][j], 0, 0, 0);
        }
        __builtin_amdgcn_s_barrier();        // all waves done reading before next STAGE overwrites
        __builtin_amdgcn_sched_barrier(0);
    }

    // ---- epilogue: C-write + fused BN partial sums ----
#pragma unroll
    for (int j = 0; j < 4; ++j) {
        int n = rowB0 + wc * 64 + j * 16 + l15;
        float bs = bias[n];
        float s = 0.f, q2 = 0.f;
#pragma unroll
        for (int i = 0; i < 4; ++i)
#pragma unroll
            for (int q = 0; q < 4; ++q) {
                int ml = rowA0 + wr * 64 + i * 16 + hi * 4 + q;   // local chunk row
                float v = acc[i][j][q] + bs;
                Cg[(size_t)ml * HID + n] = f2b(v);
                if (m0 + ml < NN) { s += v; q2 += v * v; }        // exclude padding rows
            }
        s  += __shfl_down(s, 32);  s  += __shfl_down(s, 16);
        q2 += __shfl_down(q2, 32); q2 += __shfl_down(q2, 16);
        if (lane < 16) { sred[wr][wc][j][l15][0] = s; sred[wr][wc][j][l15][1] = q2; }
    }
    __syncthreads();
    if (t < 128) {   // one thread per block column
        int wcc = t >> 6, j = (t >> 4) & 3, li = t & 15;
        float s  = sred[0][wcc][j][li][0] + sred[1][wcc][j][li][0];
        float q2 = sred[0][wcc][j][li][1] + sred[1][wcc][j][li][1];
        int slot = (m0 >> 7) + bm;          // global 128-row slot, unique per (layer, slot)
        int cg = rowB0 + t;                 // global column 0..255
        partialC[(size_t)slot * 512 + cg] = s;
        partialC[(size_t)slot * 512 + 256 + cg] = q2;
    }
}

// ---------------- BN reduce (deterministic, hierarchical) ----------------
__global__ void bn_red1(const float* __restrict__ pc, float* __restrict__ t2) {
    int b = blockIdx.x;      // 64
    int ch = threadIdx.x;    // 256
    float s0 = 0.f, s1 = 0.f;
    for (int s = b; s < NSLOT; s += 64) {
        s0 += pc[(size_t)s * 512 + ch];
        s1 += pc[(size_t)s * 512 + 256 + ch];
    }
    t2[b * 512 + ch] = s0;
    t2[b * 512 + 256 + ch] = s1;
}

// MUST be launched with exactly HID(=256) threads; guard enforces the contract.
__global__ void bn_fin2(const float* __restrict__ t2, float* __restrict__ mi) {
    int ch = threadIdx.x;
    if (ch >= HID) return;
    float s = 0.f, q2 = 0.f;
    for (int b = 0; b < 64; ++b) {
        s += t2[b * 512 + ch];
        q2 += t2[b * 512 + 256 + ch];
    }
    float mean = s / (float)NN;
    float var = q2 / (float)NN - mean * mean;
    if (var < 0.f) var = 0.f;
    mi[ch] = mean;
    mi[HID + ch] = rsqrtf(var + BN_EPS);
}

// relu(bn(C)) -> bf16 into X2 (stride 256)
__global__ void bn_relu(const unsigned short* __restrict__ Cin, const float* __restrict__ mi,
                        const float* __restrict__ gamma, const float* __restrict__ beta,
                        unsigned short* __restrict__ Xout) {
    int tid = blockIdx.x * 256 + threadIdx.x;  // NN*64 threads (exact)
    int i = tid >> 6;
    int ch = (tid & 63) << 2;
    ushort4 v = *(const ushort4*)(Cin + (size_t)i * HID + ch);
    float vv[4] = { b2f(v.x), b2f(v.y), b2f(v.z), b2f(v.w) };
    ushort4 o;
    unsigned short* op = (unsigned short*)&o;
#pragma unroll
    for (int q = 0; q < 4; ++q) {
        int c = ch + q;
        float y = gamma[c] * (vv[q] - mi[c]) * mi[HID + c] + beta[c];
        op[q] = f2b(fmaxf(y, 0.f));
    }
    *(ushort4*)(Xout + (size_t)i * HID + ch) = o;
}

// fused bn2 + relu + classifier for tx rows: one wave per row
__global__ __launch_bounds__(256) void classify(
    const unsigned short* __restrict__ Cin, const float* __restrict__ mi,
    const float* __restrict__ gamma, const float* __restrict__ beta,
    const float* __restrict__ cw, const float* __restrict__ cb,
    float* __restrict__ out) {
    int w = threadIdx.x >> 6, lane = threadIdx.x & 63;
    int i = blockIdx.x * 4 + w;
    if (i >= NUM_TX) return;
    int ch = lane << 2;
    ushort4 v = *(const ushort4*)(Cin + (size_t)i * HID + ch);
    float vv[4] = { b2f(v.x), b2f(v.y), b2f(v.z), b2f(v.w) };
    float a0 = 0.f, a1 = 0.f;
#pragma unroll
    for (int q = 0; q < 4; ++q) {
        int c = ch + q;
        float y = gamma[c] * (vv[q] - mi[c]) * mi[HID + c] + beta[c];
        y = fmaxf(y, 0.f);
        a0 += y * cw[c * 2 + 0];
        a1 += y * cw[c * 2 + 1];
    }
#pragma unroll
    for (int d = 32; d; d >>= 1) { a0 += __shfl_down(a0, d); a1 += __shfl_down(a1, d); }
    if (lane == 0) {
        out[(size_t)i * 2 + 0] = a0 + cb[0];
        out[(size_t)i * 2 + 1] = a1 + cb[1];
    }
}

// ---------------- launch ----------------
extern "C" void kernel_launch(void* const* d_in, const int* in_sizes, int n_in,
                              void* d_out, int out_size, void* d_ws, size_t ws_size,
                              hipStream_t stream) {
    const float* x_tx   = (const float*)d_in[0];
    const float* ue     = (const float*)d_in[1];
    const float* de     = (const float*)d_in[2];
    const float* relw1  = (const float*)d_in[3];
    const float* rootw1 = (const float*)d_in[4];
    const float* bias1  = (const float*)d_in[5];
    const float* relw2  = (const float*)d_in[6];
    const float* rootw2 = (const float*)d_in[7];
    const float* bias2  = (const float*)d_in[8];
    const float* g1     = (const float*)d_in[9];
    const float* be1    = (const float*)d_in[10];
    const float* g2     = (const float*)d_in[11];
    const float* be2    = (const float*)d_in[12];
    const float* cw     = (const float*)d_in[13];
    const float* cb     = (const float*)d_in[14];
    const int*   ei     = (const int*)d_in[15];
    const int*   et     = (const int*)d_in[16];
    float* out = (float*)d_out;
    (void)in_sizes; (void)n_in;

    // ---- fixed workspace layout (~162 MB) ----
    char* p = (char*)d_ws;
    auto take = [&](size_t b) { char* r = p; p += (b + 255) & ~(size_t)255; return r; };
    unsigned short* X  = (unsigned short*)take((size_t)MP * HID * 2);  // X1 stride 128 / X2 stride 256
    unsigned short* Cb = (unsigned short*)take((size_t)MP * HID * 2);  // pre-BN activations, bf16
    unsigned short* Wt1 = (unsigned short*)take((size_t)HID * 640 * 2);
    unsigned short* Wt2 = (unsigned short*)take((size_t)HID * 1280 * 2);
    int* ecnt  = (int*)take((size_t)NN * 4);
    int* eoff  = (int*)take((size_t)(NN + 1) * 4);
    int* sedge = (int*)take((size_t)NEDGE * 4);
    unsigned long long* ptmp = (unsigned long long*)take((size_t)NEDGE * 8);
    int* pctr  = (int*)take((size_t)NPART * 16 * 4);   // padded: 1 line per counter
    int* bsum  = (int*)take((size_t)SCAN_NB * 4);
    float* partialC = (float*)take((size_t)NSLOT * 512 * 4);
    float* t2red    = (float*)take((size_t)64 * 512 * 4);
    float* mi1 = (float*)take(512 * 4);
    float* mi2 = (float*)take(512 * 4);
    size_t fixed = (size_t)(p - (char*)d_ws);

    // ---- adaptive AGG-chunk: CH rows of [4*256] bf16 (layer2 worst case) ----
    long long rem = (long long)ws_size - (long long)fixed;
    long long chv = rem / (4 * HID * 2);
    int CH = (chv >= 128) ? (int)(chv & ~127LL) : 0;
    if (CH > CH_CAP) CH = CH_CAP;
    if (CH < 128) {
        mark_ws<<<(out_size + 255) / 256, 256, 0, stream>>>(out, out_size, (float)(ws_size >> 20));
        return;
    }
    unsigned short* Achunk = (unsigned short*)take((size_t)CH * 4 * HID * 2);

    hipMemsetAsync(ecnt, 0, (size_t)NN * 4, stream);
    hipMemsetAsync(pctr, 0, (size_t)NPART * 16 * 4, stream);

    count_edges<<<(NEDGE + 255) / 256, 256, 0, stream>>>(ei, ecnt);
    scan_bsum<<<SCAN_NB, 256, 0, stream>>>(ecnt, bsum);
    scan_bscan<<<1, 1024, 0, stream>>>(bsum);
    scan_final<<<SCAN_NB, 256, 0, stream>>>(ecnt, bsum, eoff);
    scatter_part1<<<P1_NB, 256, 0, stream>>>(ei, et, eoff, pctr, ptmp);
    scatter_part2<<<NPART, 1024, 0, stream>>>(eoff, ptmp, sedge);

    build_x0<<<NN * 32 / 256, 256, 0, stream>>>(x_tx, ue, de, X);
    build_wt<<<640, 256, 0, stream>>>(rootw1, relw1, Wt1, 640, 128);
    build_wt<<<1280, 256, 0, stream>>>(rootw2, relw2, Wt2, 1280, 256);

    // ---- layer 1 (C_in = 128, K = 640) ----
    for (int m0 = 0; m0 < MP; m0 += CH) {
        int rows = (MP - m0 < CH) ? (MP - m0) : CH;
        int mb = rows / 128;
        int grid = ((mb * 2 + 15) / 16) * 16;   // round up for the XCD-pair swizzle
        aggregate<128><<<rows / 4, 256, 0, stream>>>(X, Achunk, eoff, sedge, m0);
        gemm_split<128><<<grid, 256, 0, stream>>>(X, Achunk, Wt1, Cb + (size_t)m0 * HID, bias1, partialC, mb, m0);
    }
    bn_red1<<<64, 256, 0, stream>>>(partialC, t2red);
    bn_fin2<<<1, 256, 0, stream>>>(t2red, mi1);
    bn_relu<<<NN * 64 / 256, 256, 0, stream>>>(Cb, mi1, g1, be1, X);

    // ---- layer 2 (C_in = 256, K = 1280) ----
    for (int m0 = 0; m0 < MP; m0 += CH) {
        int rows = (MP - m0 < CH) ? (MP - m0) : CH;
        int mb = rows / 128;
        int grid = ((mb * 2 + 15) / 16) * 16;
        aggregate<256><<<rows / 4, 256, 0, stream>>>(X, Achunk, eoff, sedge, m0);
        gemm_split<256><<<grid, 256, 0, stream>>>(X, Achunk, Wt2, Cb + (size_t)m0 * HID, bias2, partialC, mb, m0);
    }
    bn_red1<<<64, 256, 0, stream>>>(partialC, t2red);
    bn_fin2<<<1, 256, 0, stream>>>(t2red, mi2);
    classify<<<NUM_TX / 4, 256, 0, stream>>>(Cb, mi2, g2, be2, cw, cb, out);
}

// Round 14
// 620.676 us; speedup vs baseline: 1.3841x; 1.0489x over previous
//
#include <hip/hip_runtime.h>
#include <hip/hip_bf16.h>

#define NUM_TX   100000
#define NUM_USER 30000
#define NUM_DEV  10000
#define NN       140000   // total nodes
#define MP       140032   // NN padded to multiple of 128
#define NSLOT    1094     // MP/128 row-block slots
#define INC      128
#define HID      256
#define NEDGE    1000000
#define BN_EPS   1e-5f
#define NPART    137      // ceil(NN/1024) dst partitions
#define P1_NB    500      // histogram/scatter pass-1 blocks
#define P1_CHUNK 2000     // NEDGE / P1_NB (exact)
#define CH_CAP   35072    // chunk-row cap (multiple of 128): AGG chunk <= 71.8 MB for L3 residency

typedef __attribute__((ext_vector_type(8))) short bf16x8;
typedef __attribute__((ext_vector_type(4))) float f32x4;

__device__ __forceinline__ float b2f(unsigned short s) {
    union { unsigned int u; float f; } c; c.u = ((unsigned int)s) << 16; return c.f;
}
__device__ __forceinline__ unsigned short f2b(float f) {
    union { __hip_bfloat16 h; unsigned short s; } c; c.h = __float2bfloat16(f); return c.s;
}

// ---------------- diagnostic fallback: encode ws_size into the output ----------------
__global__ void mark_ws(float* __restrict__ out, int n, float val) {
    int i = blockIdx.x * 256 + threadIdx.x;
    if (i < n) out[i] = val;
}

// ---------------- CSR build (no per-node global atomics anywhere) ----------------
// Stage 1: per-block LDS histogram over 137 partitions -> padded global counters.
// (r13: count_edges' 1M random atomics caused 31MB of partial-line writebacks.)
__global__ __launch_bounds__(256) void part_hist(const int* __restrict__ ei,
                                                 int* __restrict__ pcount) {
    __shared__ int hist[NPART];
    int b = blockIdx.x, t = threadIdx.x;
    int e0 = b * P1_CHUNK, e1 = e0 + P1_CHUNK;
    for (int i = t; i < NPART; i += 256) hist[i] = 0;
    __syncthreads();
    for (int e = e0 + t; e < e1; e += 256)
        atomicAdd(&hist[ei[NEDGE + e] >> 10], 1);
    __syncthreads();
    if (t < NPART && hist[t]) atomicAdd(&pcount[t * 16], hist[t]);
}

// Stage 2: exclusive scan of the 137 partition counts (single block).
__global__ void scan_poff(const int* __restrict__ pcount, int* __restrict__ poff) {
    __shared__ int ss[256];
    int t = threadIdx.x;
    int v = (t < NPART) ? pcount[t * 16] : 0;
    ss[t] = v;
    __syncthreads();
    for (int d = 1; d < 256; d <<= 1) {
        int u = (t >= d) ? ss[t - d] : 0;
        __syncthreads();
        ss[t] += u;
        __syncthreads();
    }
    if (t < NPART) poff[t] = ss[t] - v;
    if (t == NPART - 1) poff[NPART] = ss[t];   // = NEDGE
}

// Stage 3: append packed edge records into partition regions (full-line writes).
__global__ __launch_bounds__(256) void scatter_part1(
    const int* __restrict__ ei, const int* __restrict__ et,
    const int* __restrict__ poff, int* __restrict__ pctr,
    unsigned long long* __restrict__ ptmp) {
    __shared__ int hist[NPART];
    __shared__ int base[NPART];
    __shared__ int runc[NPART];
    int b = blockIdx.x, t = threadIdx.x;
    int e0 = b * P1_CHUNK, e1 = e0 + P1_CHUNK;
    for (int i = t; i < NPART; i += 256) { hist[i] = 0; runc[i] = 0; }
    __syncthreads();
    for (int e = e0 + t; e < e1; e += 256)
        atomicAdd(&hist[ei[NEDGE + e] >> 10], 1);
    __syncthreads();
    if (t < NPART)
        base[t] = poff[t] + atomicAdd(&pctr[t * 16], hist[t]);  // padded counters: 1 line each
    __syncthreads();
    for (int e = e0 + t; e < e1; e += 256) {
        int dst = ei[NEDGE + e];
        int p = dst >> 10;
        int r = atomicAdd(&runc[p], 1);
        unsigned long long w = (unsigned long long)(unsigned)ei[e]
                             | ((unsigned long long)(unsigned)et[e] << 18)
                             | ((unsigned long long)(unsigned)dst << 20);
        ptmp[(size_t)base[p] + r] = w;
    }
}

// Stage 4: one block per partition. Per-node counts in LDS, in-block scan writes
// eoff[] directly, second pass places edges inside the L2-resident window.
__global__ __launch_bounds__(1024) void scatter_part2(
    const int* __restrict__ poff, const unsigned long long* __restrict__ ptmp,
    int* __restrict__ eoff, int* __restrict__ sedge) {
    __shared__ int lcnt[1024];
    __shared__ int lpre[1024];
    __shared__ int lrun[1024];
    int p = blockIdx.x, t = threadIdx.x;
    int n0 = p << 10;
    lcnt[t] = 0; lrun[t] = 0;
    __syncthreads();
    int lo = poff[p], hi = poff[p + 1];
    for (int j = lo + t; j < hi; j += 1024)
        atomicAdd(&lcnt[(int)(ptmp[j] >> 20) - n0], 1);
    __syncthreads();
    int v = lcnt[t];
    lpre[t] = v;
    __syncthreads();
    for (int d = 1; d < 1024; d <<= 1) {
        int u = (t >= d) ? lpre[t - d] : 0;
        __syncthreads();
        lpre[t] += u;
        __syncthreads();
    }
    int gi = n0 + t;
    if (gi <= NN) eoff[gi] = lo + lpre[t] - v;   // exclusive prefix; gi==NN lands hi
    __syncthreads();
    for (int j = lo + t; j < hi; j += 1024) {
        unsigned long long w = ptmp[j];
        int src = (int)(w & 0x3FFFF);
        int rel = (int)((w >> 18) & 3);
        int local = (int)(w >> 20) - n0;
        int r = atomicAdd(&lrun[local], 1);
        sedge[lo + lpre[local] - lcnt[local] + r] = src | (rel << 28);
    }
}

// ---------------- input / weight staging ----------------
__global__ void build_x0(const float* __restrict__ xt, const float* __restrict__ ue,
                         const float* __restrict__ de, unsigned short* __restrict__ X) {
    int tid = blockIdx.x * 256 + threadIdx.x;   // NN*32 threads (exact)
    int i = tid >> 5;
    int c4 = (tid & 31) << 2;
    const float* s;
    if (i < NUM_TX) s = xt + (size_t)i * INC;
    else if (i < NUM_TX + NUM_USER) s = ue + (size_t)(i - NUM_TX) * INC;
    else s = de + (size_t)(i - NUM_TX - NUM_USER) * INC;
    float4 v = *(const float4*)(s + c4);
    ushort4 o;
    o.x = f2b(v.x); o.y = f2b(v.y); o.z = f2b(v.z); o.w = f2b(v.w);
    *(ushort4*)(X + (size_t)i * INC + c4) = o;
}

// Wt[n*K + k] = bf16( k<rootK ? root[k][n] : rel[(k-rootK)][n] )  (n-major for GEMM B^T)
__global__ void build_wt(const float* __restrict__ rootw, const float* __restrict__ relw,
                         unsigned short* __restrict__ Wt, int K, int rootK) {
    int tid = blockIdx.x * 256 + threadIdx.x;   // 256*K threads (grid = K blocks, exact)
    int n = tid / K, k = tid - n * K;
    float v = (k < rootK) ? rootw[(size_t)k * HID + n] : relw[(size_t)(k - rootK) * HID + n];
    Wt[tid] = f2b(v);
}

// ---------------- segmented mean aggregation (scalarized edge walk, r13 win) ----------------
template<int C>
__global__ __launch_bounds__(256) void aggregate(
    const unsigned short* __restrict__ X, unsigned short* __restrict__ AGG,
    const int* __restrict__ eoff, const int* __restrict__ sedge, int m0) {
    constexpr int V = C / 64;
    int w = threadIdx.x >> 6, lane = threadIdx.x & 63;
    int i = m0 + blockIdx.x * 4 + w;
    if (i >= NN) return;
    float a0[V] = {}, a1[V] = {}, a2[V] = {}, a3[V] = {};
    int c0 = 0, c1 = 0, c2 = 0, c3 = 0;
    int b = eoff[i], e = eoff[i + 1];
    const unsigned short* Xl = X + (size_t)lane * V;   // lane offset folded once
    for (int p0 = b; p0 < e; p0 += 64) {
        int nb = e - p0; if (nb > 64) nb = 64;
        int myedge = (p0 + lane < e) ? sedge[p0 + lane] : 0;   // coalesced batch load
        for (int q = 0; q < nb; ++q) {
            int pe = __builtin_amdgcn_readlane(myedge, q);     // SGPR: uniform proven
            int src = pe & 0x0FFFFFFF;
            int r = pe >> 28;
            const unsigned short* row = Xl + (size_t)src * C;
            float v[V];
            if constexpr (V == 2) {
                unsigned int u = *(const unsigned int*)row;
                v[0] = b2f((unsigned short)(u & 0xFFFF));
                v[1] = b2f((unsigned short)(u >> 16));
            } else {
                ushort4 u = *(const ushort4*)row;
                v[0] = b2f(u.x); v[1] = b2f(u.y); v[2] = b2f(u.z); v[3] = b2f(u.w);
            }
            if (r == 0)      { for (int j = 0; j < V; ++j) a0[j] += v[j]; c0++; }
            else if (r == 1) { for (int j = 0; j < V; ++j) a1[j] += v[j]; c1++; }
            else if (r == 2) { for (int j = 0; j < V; ++j) a2[j] += v[j]; c2++; }
            else             { for (int j = 0; j < V; ++j) a3[j] += v[j]; c3++; }
        }
    }
    float s0 = 1.0f / (float)(c0 > 1 ? c0 : 1);
    float s1 = 1.0f / (float)(c1 > 1 ? c1 : 1);
    float s2 = 1.0f / (float)(c2 > 1 ? c2 : 1);
    float s3 = 1.0f / (float)(c3 > 1 ? c3 : 1);
    unsigned short* orow = AGG + (size_t)(i - m0) * (4 * C) + lane * V;
#pragma unroll
    for (int j = 0; j < V; ++j) {
        orow[0 * C + j] = f2b(a0[j] * s0);
        orow[1 * C + j] = f2b(a1[j] * s1);
        orow[2 * C + j] = f2b(a2[j] * s2);
        orow[3 * C + j] = f2b(a3[j] * s3);
    }
}

// ---------------- bf16 MFMA GEMM (single-buffer m97-style, r12 win) ----------------
// Keeps: split-source A, XOR-swizzled LDS (conflicts=0), XCD-pairing, fused BN.
template<int C>
__global__ __launch_bounds__(256) void gemm_split(
    const unsigned short* __restrict__ Xg, const unsigned short* __restrict__ AGGg,
    const unsigned short* __restrict__ Wt, unsigned short* __restrict__ Cg,
    const float* __restrict__ bias, float* __restrict__ partialC, int mblocks, int m0) {
    constexpr int K = 5 * C;
    constexpr int NKT = K / 64;
    constexpr int XKT = C / 64;
    __shared__ unsigned short As[128 * 64];
    __shared__ unsigned short Bs[128 * 64];
    __shared__ float sred[2][2][4][16][2];   // [wr][wc][j][l15][{s,s2}]
    int bid = blockIdx.x;
    int bm = (bid & 7) + ((bid >> 4) << 3);
    int bn = (bid >> 3) & 1;
    if (bm >= mblocks) return;               // pad blocks from grid round-up
    int t = threadIdx.x;
    int lane = t & 63, w = t >> 6;
    int wr = w >> 1, wc = w & 1;
    int l15 = lane & 15, l7 = lane & 7, hi = lane >> 4;
    f32x4 acc[4][4] = {};
    const int rowA0 = bm * 128, rowB0 = bn * 128;

    auto STAGE = [&](int kt) {
#pragma unroll
        for (int it = 0; it < 4; ++it) {
            int R = it * 32 + (t >> 3);
            int sl = (t & 7) ^ (R & 7);           // pre-swizzled global slot
            const unsigned short* ga;
            if (kt < XKT)
                ga = Xg + (size_t)(m0 + rowA0 + R) * C + kt * 64 + sl * 8;
            else
                ga = AGGg + (size_t)(rowA0 + R) * (4 * C) + (kt - XKT) * 64 + sl * 8;
            __builtin_amdgcn_global_load_lds(
                (const __attribute__((address_space(1))) void*)ga,
                (__attribute__((address_space(3))) void*)(As + it * 2048 + t * 8), 16, 0, 0);
            const unsigned short* gb = Wt + (size_t)(rowB0 + R) * K + kt * 64 + sl * 8;
            __builtin_amdgcn_global_load_lds(
                (const __attribute__((address_space(1))) void*)gb,
                (__attribute__((address_space(3))) void*)(Bs + it * 2048 + t * 8), 16, 0, 0);
        }
    };

    for (int kt = 0; kt < NKT; ++kt) {
        STAGE(kt);
        asm volatile("s_waitcnt vmcnt(0)" ::: "memory");
        __builtin_amdgcn_s_barrier();
        __builtin_amdgcn_sched_barrier(0);
#pragma unroll
        for (int kk = 0; kk < 64; kk += 32) {
            bf16x8 af[4], bfr[4];
            int sl2 = (((kk >> 3) + hi) ^ l7) << 3;
#pragma unroll
            for (int f = 0; f < 4; ++f) {
                int m = wr * 64 + f * 16 + l15;
                af[f] = *(const bf16x8*)(As + m * 64 + sl2);
                int n = wc * 64 + f * 16 + l15;
                bfr[f] = *(const bf16x8*)(Bs + n * 64 + sl2);
            }
#pragma unroll
            for (int i = 0; i < 4; ++i)
#pragma unroll
                for (int j = 0; j < 4; ++j)
                    acc[i][j] = __builtin_amdgcn_mfma_f32_16x16x32_bf16(af[i], bfr[j], acc[i][j], 0, 0, 0);
        }
        __builtin_amdgcn_s_barrier();        // all waves done reading before next STAGE overwrites
        __builtin_amdgcn_sched_barrier(0);
    }

    // ---- epilogue: C-write + fused BN partial sums ----
#pragma unroll
    for (int j = 0; j < 4; ++j) {
        int n = rowB0 + wc * 64 + j * 16 + l15;
        float bs = bias[n];
        float s = 0.f, q2 = 0.f;
#pragma unroll
        for (int i = 0; i < 4; ++i)
#pragma unroll
            for (int q = 0; q < 4; ++q) {
                int ml = rowA0 + wr * 64 + i * 16 + hi * 4 + q;   // local chunk row
                float v = acc[i][j][q] + bs;
                Cg[(size_t)ml * HID + n] = f2b(v);
                if (m0 + ml < NN) { s += v; q2 += v * v; }        // exclude padding rows
            }
        s  += __shfl_down(s, 32);  s  += __shfl_down(s, 16);
        q2 += __shfl_down(q2, 32); q2 += __shfl_down(q2, 16);
        if (lane < 16) { sred[wr][wc][j][l15][0] = s; sred[wr][wc][j][l15][1] = q2; }
    }
    __syncthreads();
    if (t < 128) {   // one thread per block column
        int wcc = t >> 6, j = (t >> 4) & 3, li = t & 15;
        float s  = sred[0][wcc][j][li][0] + sred[1][wcc][j][li][0];
        float q2 = sred[0][wcc][j][li][1] + sred[1][wcc][j][li][1];
        int slot = (m0 >> 7) + bm;          // global 128-row slot, unique per (layer, slot)
        int cg = rowB0 + t;                 // global column 0..255
        partialC[(size_t)slot * 512 + cg] = s;
        partialC[(size_t)slot * 512 + 256 + cg] = q2;
    }
}

// ---------------- BN reduce (deterministic, hierarchical) ----------------
__global__ void bn_red1(const float* __restrict__ pc, float* __restrict__ t2) {
    int b = blockIdx.x;      // 64
    int ch = threadIdx.x;    // 256
    float s0 = 0.f, s1 = 0.f;
    for (int s = b; s < NSLOT; s += 64) {
        s0 += pc[(size_t)s * 512 + ch];
        s1 += pc[(size_t)s * 512 + 256 + ch];
    }
    t2[b * 512 + ch] = s0;
    t2[b * 512 + 256 + ch] = s1;
}

// MUST be launched with exactly HID(=256) threads; guard enforces the contract.
__global__ void bn_fin2(const float* __restrict__ t2, float* __restrict__ mi) {
    int ch = threadIdx.x;
    if (ch >= HID) return;
    float s = 0.f, q2 = 0.f;
    for (int b = 0; b < 64; ++b) {
        s += t2[b * 512 + ch];
        q2 += t2[b * 512 + 256 + ch];
    }
    float mean = s / (float)NN;
    float var = q2 / (float)NN - mean * mean;
    if (var < 0.f) var = 0.f;
    mi[ch] = mean;
    mi[HID + ch] = rsqrtf(var + BN_EPS);
}

// relu(bn(C)) -> bf16 into X2 (stride 256)
__global__ void bn_relu(const unsigned short* __restrict__ Cin, const float* __restrict__ mi,
                        const float* __restrict__ gamma, const float* __restrict__ beta,
                        unsigned short* __restrict__ Xout) {
    int tid = blockIdx.x * 256 + threadIdx.x;  // NN*64 threads (exact)
    int i = tid >> 6;
    int ch = (tid & 63) << 2;
    ushort4 v = *(const ushort4*)(Cin + (size_t)i * HID + ch);
    float vv[4] = { b2f(v.x), b2f(v.y), b2f(v.z), b2f(v.w) };
    ushort4 o;
    unsigned short* op = (unsigned short*)&o;
#pragma unroll
    for (int q = 0; q < 4; ++q) {
        int c = ch + q;
        float y = gamma[c] * (vv[q] - mi[c]) * mi[HID + c] + beta[c];
        op[q] = f2b(fmaxf(y, 0.f));
    }
    *(ushort4*)(Xout + (size_t)i * HID + ch) = o;
}

// fused bn2 + relu + classifier for tx rows: one wave per row
__global__ __launch_bounds__(256) void classify(
    const unsigned short* __restrict__ Cin, const float* __restrict__ mi,
    const float* __restrict__ gamma, const float* __restrict__ beta,
    const float* __restrict__ cw, const float* __restrict__ cb,
    float* __restrict__ out) {
    int w = threadIdx.x >> 6, lane = threadIdx.x & 63;
    int i = blockIdx.x * 4 + w;
    if (i >= NUM_TX) return;
    int ch = lane << 2;
    ushort4 v = *(const ushort4*)(Cin + (size_t)i * HID + ch);
    float vv[4] = { b2f(v.x), b2f(v.y), b2f(v.z), b2f(v.w) };
    float a0 = 0.f, a1 = 0.f;
#pragma unroll
    for (int q = 0; q < 4; ++q) {
        int c = ch + q;
        float y = gamma[c] * (vv[q] - mi[c]) * mi[HID + c] + beta[c];
        y = fmaxf(y, 0.f);
        a0 += y * cw[c * 2 + 0];
        a1 += y * cw[c * 2 + 1];
    }
#pragma unroll
    for (int d = 32; d; d >>= 1) { a0 += __shfl_down(a0, d); a1 += __shfl_down(a1, d); }
    if (lane == 0) {
        out[(size_t)i * 2 + 0] = a0 + cb[0];
        out[(size_t)i * 2 + 1] = a1 + cb[1];
    }
}

// ---------------- launch ----------------
extern "C" void kernel_launch(void* const* d_in, const int* in_sizes, int n_in,
                              void* d_out, int out_size, void* d_ws, size_t ws_size,
                              hipStream_t stream) {
    const float* x_tx   = (const float*)d_in[0];
    const float* ue     = (const float*)d_in[1];
    const float* de     = (const float*)d_in[2];
    const float* relw1  = (const float*)d_in[3];
    const float* rootw1 = (const float*)d_in[4];
    const float* bias1  = (const float*)d_in[5];
    const float* relw2  = (const float*)d_in[6];
    const float* rootw2 = (const float*)d_in[7];
    const float* bias2  = (const float*)d_in[8];
    const float* g1     = (const float*)d_in[9];
    const float* be1    = (const float*)d_in[10];
    const float* g2     = (const float*)d_in[11];
    const float* be2    = (const float*)d_in[12];
    const float* cw     = (const float*)d_in[13];
    const float* cb     = (const float*)d_in[14];
    const int*   ei     = (const int*)d_in[15];
    const int*   et     = (const int*)d_in[16];
    float* out = (float*)d_out;
    (void)in_sizes; (void)n_in;

    // ---- fixed workspace layout (~162 MB) ----
    char* p = (char*)d_ws;
    auto take = [&](size_t b) { char* r = p; p += (b + 255) & ~(size_t)255; return r; };
    unsigned short* X  = (unsigned short*)take((size_t)MP * HID * 2);  // X1 stride 128 / X2 stride 256
    unsigned short* Cb = (unsigned short*)take((size_t)MP * HID * 2);  // pre-BN activations, bf16
    unsigned short* Wt1 = (unsigned short*)take((size_t)HID * 640 * 2);
    unsigned short* Wt2 = (unsigned short*)take((size_t)HID * 1280 * 2);
    int* eoff  = (int*)take((size_t)(NN + 1) * 4);
    int* sedge = (int*)take((size_t)NEDGE * 4);
    unsigned long long* ptmp = (unsigned long long*)take((size_t)NEDGE * 8);
    int* pcount = (int*)take((size_t)NPART * 16 * 4);  // padded: 1 line per counter
    int* pctr   = (int*)take((size_t)NPART * 16 * 4);
    int* poff   = (int*)take((size_t)(NPART + 1) * 4);
    float* partialC = (float*)take((size_t)NSLOT * 512 * 4);
    float* t2red    = (float*)take((size_t)64 * 512 * 4);
    float* mi1 = (float*)take(512 * 4);
    float* mi2 = (float*)take(512 * 4);
    size_t fixed = (size_t)(p - (char*)d_ws);

    // ---- adaptive AGG-chunk: CH rows of [4*256] bf16 (layer2 worst case) ----
    long long rem = (long long)ws_size - (long long)fixed;
    long long chv = rem / (4 * HID * 2);
    int CH = (chv >= 128) ? (int)(chv & ~127LL) : 0;
    if (CH > CH_CAP) CH = CH_CAP;
    if (CH < 128) {
        mark_ws<<<(out_size + 255) / 256, 256, 0, stream>>>(out, out_size, (float)(ws_size >> 20));
        return;
    }
    unsigned short* Achunk = (unsigned short*)take((size_t)CH * 4 * HID * 2);

    hipMemsetAsync(pcount, 0, (size_t)NPART * 16 * 4, stream);
    hipMemsetAsync(pctr, 0, (size_t)NPART * 16 * 4, stream);

    part_hist<<<P1_NB, 256, 0, stream>>>(ei, pcount);
    scan_poff<<<1, 256, 0, stream>>>(pcount, poff);
    scatter_part1<<<P1_NB, 256, 0, stream>>>(ei, et, poff, pctr, ptmp);
    scatter_part2<<<NPART, 1024, 0, stream>>>(poff, ptmp, eoff, sedge);

    build_x0<<<NN * 32 / 256, 256, 0, stream>>>(x_tx, ue, de, X);
    build_wt<<<640, 256, 0, stream>>>(rootw1, relw1, Wt1, 640, 128);
    build_wt<<<1280, 256, 0, stream>>>(rootw2, relw2, Wt2, 1280, 256);

    // ---- layer 1 (C_in = 128, K = 640) ----
    for (int m0 = 0; m0 < MP; m0 += CH) {
        int rows = (MP - m0 < CH) ? (MP - m0) : CH;
        int mb = rows / 128;
        int grid = ((mb * 2 + 15) / 16) * 16;   // round up for the XCD-pair swizzle
        aggregate<128><<<rows / 4, 256, 0, stream>>>(X, Achunk, eoff, sedge, m0);
        gemm_split<128><<<grid, 256, 0, stream>>>(X, Achunk, Wt1, Cb + (size_t)m0 * HID, bias1, partialC, mb, m0);
    }
    bn_red1<<<64, 256, 0, stream>>>(partialC, t2red);
    bn_fin2<<<1, 256, 0, stream>>>(t2red, mi1);
    bn_relu<<<NN * 64 / 256, 256, 0, stream>>>(Cb, mi1, g1, be1, X);

    // ---- layer 2 (C_in = 256, K = 1280) ----
    for (int m0 = 0; m0 < MP; m0 += CH) {
        int rows = (MP - m0 < CH) ? (MP - m0) : CH;
        int mb = rows / 128;
        int grid = ((mb * 2 + 15) / 16) * 16;
        aggregate<256><<<rows / 4, 256, 0, stream>>>(X, Achunk, eoff, sedge, m0);
        gemm_split<256><<<grid, 256, 0, stream>>>(X, Achunk, Wt2, Cb + (size_t)m0 * HID, bias2, partialC, mb, m0);
    }
    bn_red1<<<64, 256, 0, stream>>>(partialC, t2red);
    bn_fin2<<<1, 256, 0, stream>>>(t2red, mi2);
    classify<<<NUM_TX / 4, 256, 0, stream>>>(Cb, mi2, g2, be2, cw, cb, out);
}